// Round 9
// baseline (6427.682 us; speedup 1.0000x reference)
//
#include <hip/hip_runtime.h>
#include <math.h>

#define NT 512        // time steps
#define NB 512        // batch
#define HID 128
#define NIN 10
#define NC 10         // memory cells
#define CW 20         // cell width
#define NIF 88        // interface size
#define NOUT 10
#define GB 2          // batches per workgroup
#define BLK 512       // 8 waves; alloc law grants 128 VGPR at this size

typedef _Float16 h1;
typedef _Float16 h2 __attribute__((ext_vector_type(2)));

// ---- fast transcendentals (abs err ~1e-7, vs fp16 noise 5e-4) ----
__device__ __forceinline__ float rcpf(float x) { return __builtin_amdgcn_rcpf(x); }
__device__ __forceinline__ float sigf(float x) { return rcpf(1.0f + __expf(-x)); }
__device__ __forceinline__ float tanhf_(float x) {
  float xc = fminf(fmaxf(x, -15.f), 15.f);
  float e = __expf(2.f * xc);
  return (e - 1.f) * rcpf(e + 1.f);
}
// jax.nn.softplus == logaddexp(x, 0)
__device__ __forceinline__ float splus(float x) { return fmaxf(x, 0.0f) + __logf(1.f + __expf(-fabsf(x))); }

// fp16 pair dot with fp32 accumulate: v_dot2_f32_f16
__device__ __forceinline__ float dot2(h2 a, h2 b, float c) {
#if __has_builtin(__builtin_amdgcn_fdot2)
  return __builtin_amdgcn_fdot2(a, b, c, false);
#else
  c += (float)a.x * (float)b.x;
  c += (float)a.y * (float)b.y;
  return c;
#endif
}

// quad broadcast: every lane gets quad-lane k's value (BitMode: read (i&0x1C)|k)
__device__ __forceinline__ float bq0(float v) { return __builtin_bit_cast(float, __builtin_amdgcn_ds_swizzle(__builtin_bit_cast(int, v), 0x001C)); }
__device__ __forceinline__ float bq1(float v) { return __builtin_bit_cast(float, __builtin_amdgcn_ds_swizzle(__builtin_bit_cast(int, v), 0x003C)); }
__device__ __forceinline__ float bq2(float v) { return __builtin_bit_cast(float, __builtin_amdgcn_ds_swizzle(__builtin_bit_cast(int, v), 0x005C)); }
__device__ __forceinline__ float bq3(float v) { return __builtin_bit_cast(float, __builtin_amdgcn_ds_swizzle(__builtin_bit_cast(int, v), 0x007C)); }

// within-wave LDS ordering fence (no workgroup barrier)
#define LDSFENCE() do { asm volatile("s_waitcnt lgkmcnt(0)" ::: "memory"); \
                        __builtin_amdgcn_sched_barrier(0); } while (0)

#define BC(f) __builtin_bit_cast(h2, f)

// one float4 of packed fp16 weights (8 elems) x 8 fp16 activations, 2 batches
#define DOTF4(W, fa, fb)                                   \
  a0 = dot2(BC((W).x), BC((fa).x), a0);                    \
  a1 = dot2(BC((W).x), BC((fb).x), a1);                    \
  a2 = dot2(BC((W).y), BC((fa).y), a2);                    \
  a3 = dot2(BC((W).y), BC((fb).y), a3);                    \
  a0 = dot2(BC((W).z), BC((fa).z), a0);                    \
  a1 = dot2(BC((W).z), BC((fb).z), a1);                    \
  a2 = dot2(BC((W).w), BC((fa).w), a2);                    \
  a3 = dot2(BC((W).w), BC((fb).w), a3);

#define LSTEP(W, i, Pa, Pb) { float4 fa = (Pa)[i], fb = (Pb)[i]; DOTF4(W, fa, fb) }

__device__ __forceinline__ float4 pack8(const float* p) {
  h2 v0, v1, v2, v3;
  v0.x=(h1)p[0]; v0.y=(h1)p[1]; v1.x=(h1)p[2]; v1.y=(h1)p[3];
  v2.x=(h1)p[4]; v2.y=(h1)p[5]; v3.x=(h1)p[6]; v3.y=(h1)p[7];
  float4 r;
  r.x=__builtin_bit_cast(float,v0); r.y=__builtin_bit_cast(float,v1);
  r.z=__builtin_bit_cast(float,v2); r.w=__builtin_bit_cast(float,v3);
  return r;
}

// gate-interleaved row map: thread slot s owns gate-row R(s)
__device__ __host__ __forceinline__ int rowmap(int s) { return (s & 3) * 128 + (s >> 2); }

// ---- pack streamed weights (fp16, [chunk][slot], rows pre-remapped) into d_ws ----
__global__ __launch_bounds__(256) void dnc_pack_kernel(
    const float* __restrict__ Wih1, const float* __restrict__ Whh1, float4* __restrict__ ws)
{
  int i = blockIdx.x * 256 + threadIdx.x;   // 0..9215
  int s = i & 511, c = i >> 9;
  int R = rowmap(s);
  if (c < 16)      ws[i] = pack8(Whh1 + (size_t)R*HID + 8*c);
  else if (c < 18) ws[i] = pack8(Wih1 + (size_t)R*HID + (14 + (c-16))*8);
}

__global__ __launch_bounds__(BLK)
void dnc_quad_kernel(
    const float* __restrict__ x,
    const float* __restrict__ Wih0, const float* __restrict__ Whh0, const float* __restrict__ b0,
    const float* __restrict__ Wih1, const float* __restrict__ Whh1, const float* __restrict__ b1,
    const float* __restrict__ Wif,  const float* __restrict__ bif,
    const float* __restrict__ Wout, const float* __restrict__ bout,
    const float4* __restrict__ wsT,
    float* __restrict__ out)
{
  // ---- LDS (~144 KB -> 1 block/CU) ----
  __shared__ __align__(16) float4 s_wih1T[14][512];   // [chunk][slot]: Wih1 row R(slot), k=8c..8c+7
  __shared__ __align__(16) float4 s_wifT[16*89];      // [chunk*89+row]: Wif, stride-89 padded
  __shared__ __align__(16) float s_fp[NIF][9];        // interface partials [row][2c+b]
  __shared__ float s_bif[NIF];
  __shared__ __align__(16) h1   s_xbuf[2][GB][16];    // double-buffered x_t (10 + pad6) fp16
  __shared__ __align__(16) h1   s_rvh[GB][24];        // rv (20 + pad4) fp16
  __shared__ __align__(16) h1   s_h0h[GB][HID];
  __shared__ __align__(16) h1   s_h1h[GB][HID];
  __shared__ __align__(16) h1   s_ctrlh[GB][HID];
  __shared__ __align__(16) float s_ctrl[GB][HID];     // fp32 for epilogue
  __shared__ __align__(16) float s_mem[GB][NC][CW];
  __shared__ float s_rk[GB][CW], s_wk[GB][CW], s_er[GB][CW], s_wv[GB][CW];
  __shared__ float s_mraw[GB][3];
  __shared__ float s_sc[GB][8];     // 0:rs 1:ws 2:fg 3:ga 4:gw 5:m0 6:m1 7:m2
  __shared__ float s_usage[GB][NC], s_u[GB][NC];
  __shared__ float s_prec[GB][NC], s_prec2[GB][NC];
  __shared__ float s_link[GB][NC][NC];
  __shared__ float s_rw[GB][NC], s_ww[GB][NC];
  __shared__ float s_rv[GB][CW];
  __shared__ float s_cw[GB][NC], s_cr[GB][NC], s_fwd[GB][NC], s_bwd[GB][NC];

  const int tid = threadIdx.x;
  const int bg  = blockIdx.x * GB;
  const int R   = rowmap(tid);      // gate-row owned by this thread (gate=tid&3, unit=tid>>2)

  // ---- register weights: Wih0 padded row (5 f4) + Whh0 full row (16 f4) = 84 VGPRs ----
  float4 A0,A1,A2,A3,A4;
  float4 B0,B1,B2,B3,B4,B5,B6,B7,B8,B9,B10,B11,B12,B13,B14,B15;
  float b0r, b1r;
  {
    const float* p = Wih0 + (size_t)R * (NIN + CW);
    A0 = pack8(p);
    { h2 v0,z; v0.x=(h1)p[8]; v0.y=(h1)p[9]; z.x=(h1)0.f; z.y=(h1)0.f;
      float4 f; f.x=__builtin_bit_cast(float,v0); f.y=__builtin_bit_cast(float,z);
      f.z=f.y; f.w=f.y; A1=f; }
    A2 = pack8(p+10); A3 = pack8(p+18);
    { h2 v0,v1,z; v0.x=(h1)p[26]; v0.y=(h1)p[27]; v1.x=(h1)p[28]; v1.y=(h1)p[29];
      z.x=(h1)0.f; z.y=(h1)0.f;
      float4 f; f.x=__builtin_bit_cast(float,v0); f.y=__builtin_bit_cast(float,v1);
      f.z=__builtin_bit_cast(float,z); f.w=f.z; A4=f; }
    const float* q0 = Whh0 + (size_t)R*HID;
    B0 =pack8(q0);    B1 =pack8(q0+8);  B2 =pack8(q0+16);  B3 =pack8(q0+24);
    B4 =pack8(q0+32); B5 =pack8(q0+40); B6 =pack8(q0+48);  B7 =pack8(q0+56);
    B8 =pack8(q0+64); B9 =pack8(q0+72); B10=pack8(q0+80);  B11=pack8(q0+88);
    B12=pack8(q0+96); B13=pack8(q0+104);B14=pack8(q0+112); B15=pack8(q0+120);
    b0r = b0[R]; b1r = b1[R];
  }

  // ---- LDS weight staging (one-time, transposed, lane-contiguous, row-remapped) ----
  for (int idx = tid; idx < 14*512; idx += BLK) {
    int c = idx >> 9, s = idx & 511;
    s_wih1T[c][s] = pack8(Wih1 + (size_t)rowmap(s)*HID + 8*c);
  }
  for (int idx = tid; idx < 16*NIF; idx += BLK) {
    int j = idx / NIF, q = idx - j*NIF;
    s_wifT[j*89 + q] = pack8(Wif + (size_t)q*HID + 8*j);
  }
  if (tid < NIF) s_bif[tid] = bif[tid];

  // ---- zero-init state ----
  if (tid < GB*HID) { int b=tid>>7, j=tid&127;
    s_h0h[b][j]=(h1)0.f; s_h1h[b][j]=(h1)0.f; s_ctrlh[b][j]=(h1)0.f; s_ctrl[b][j]=0.f; }
  for (int i = tid; i < GB*NC*CW; i += BLK) { int b=i/(NC*CW), e=i%(NC*CW);
    s_mem[b][e/CW][e%CW]=0.f; }
  for (int i = tid; i < GB*NC*NC; i += BLK) { int b=i/(NC*NC), e=i%(NC*NC);
    s_link[b][e/NC][e%NC]=0.f; }
  if (tid < GB*NC) { int b=tid/NC, n=tid%NC;
    s_usage[b][n]=0.f; s_prec[b][n]=0.f; s_rw[b][n]=0.f; s_ww[b][n]=0.f; }
  if (tid < GB*CW) { int b=tid/CW, c=tid%CW; s_rv[b][c]=0.f; }
  if (tid < GB*24) { int b=tid/24, c=tid%24; s_rvh[b][c]=(h1)0.f; }
  if (tid < 2*GB*16) { int u=tid, d=u>>5, b=(u>>4)&1, i=u&15;
    float v = 0.f;
    if (d == 0 && i < NIN) v = x[((size_t)(bg+b)*NT + 0)*NIN + i];
    s_xbuf[d][b][i] = (h1)v;
  }
  // replicated LSTM cell states for unit u=tid>>2, batches A/B (all 4 quad lanes identical)
  float c0rA = 0.f, c0rB = 0.f, c1rA = 0.f, c1rB = 0.f;
  __syncthreads();

  // ---- single-batch DNC tail for step t-1 (one wave), fences not barriers ----
  auto dnc_tail = [&](int b, int lane) {
    // F-combine: xi = bif + sum of 4 partials, fused transforms
    #pragma unroll
    for (int q = lane; q < NIF; q += 64) {
      float a = s_bif[q];
      #pragma unroll
      for (int c = 0; c < 4; ++c) a += s_fp[q][2*c+b];
      if      (q < 20)  s_rk[b][q]    = tanhf_(a);
      else if (q == 20) s_sc[b][0]    = splus(a);
      else if (q < 41)  s_wk[b][q-21] = tanhf_(a);
      else if (q == 41) s_sc[b][1]    = splus(a);
      else if (q < 62)  s_er[b][q-42] = sigf(a);
      else if (q < 82)  s_wv[b][q-62] = tanhf_(a);
      else if (q == 82) s_sc[b][2]    = sigf(a);
      else if (q == 83) s_sc[b][3]    = sigf(a);
      else if (q == 84) s_sc[b][4]    = sigf(a);
      else              s_mraw[b][q-85] = a;
    }
    LDSFENCE();

    // H: usage/psi + write-content sims + modes softmax
    if (lane < NC) {
      int n = lane;
      float fg = s_sc[b][2];
      float psi = 1.f - fg * s_rw[b][n];
      float u = s_usage[b][n], w = s_ww[b][n];
      u = (u + w - u*w) * psi;
      s_usage[b][n] = u;
      s_u[b][n] = 1e-6f + (1.0f - 1e-6f) * u;
      float dot=0.f, mn=0.f, kn=0.f;
      #pragma unroll
      for (int c = 0; c < CW; ++c) {
        float m = s_mem[b][n][c], k = s_wk[b][c];
        dot += k*m; mn += m*m; kn += k*k;
      }
      s_cw[b][n] = dot * rcpf(sqrtf(kn)*sqrtf(mn) + 1e-6f) * s_sc[b][1];
    } else if (lane == NC) {
      float m0=s_mraw[b][0], m1=s_mraw[b][1], m2=s_mraw[b][2];
      float mm = fmaxf(m0, fmaxf(m1, m2));
      float e0=__expf(m0-mm), e1=__expf(m1-mm), e2=__expf(m2-mm);
      float es = rcpf(e0+e1+e2);
      s_sc[b][5]=e0*es; s_sc[b][6]=e1*es; s_sc[b][7]=e2*es;
    }
    LDSFENCE();

    // I: cw softmax + rank-based allocation + new ww
    if (lane < NC) {
      int n = lane;
      float mx = -1e30f;
      #pragma unroll
      for (int m = 0; m < NC; ++m) mx = fmaxf(mx, s_cw[b][m]);
      float sm = 0.f;
      #pragma unroll
      for (int m = 0; m < NC; ++m) sm += __expf(s_cw[b][m]-mx);
      float cwv = __expf(s_cw[b][n]-mx) * rcpf(sm);
      float un = s_u[b][n];
      float excl = 1.f;
      #pragma unroll
      for (int m = 0; m < NC; ++m) {
        float um = s_u[b][m];
        bool before = (um < un) || (um == un && m < n);
        excl *= before ? um : 1.f;
      }
      float alloc = (1.f - un) * excl;
      float ga = s_sc[b][3], gw = s_sc[b][4];
      s_ww[b][n] = gw * (ga*alloc + (1.f-ga)*cwv);
    }
    LDSFENCE();

    // J: memory write + link update (old prec) + prec2
    #pragma unroll
    for (int e = lane; e < NC*CW; e += 64) {
      int rr = e/CW, c = e%CW;
      float w = s_ww[b][rr];
      s_mem[b][rr][c] = s_mem[b][rr][c] * (1.f - w*s_er[b][c]) + w*s_wv[b][c];
    }
    #pragma unroll
    for (int e = lane; e < NC*NC; e += 64) {
      int i = e/NC, j = e%NC;
      float wi = s_ww[b][i], wj = s_ww[b][j];
      float l = (1.f - wi - wj)*s_link[b][i][j] + wi*s_prec[b][j];
      s_link[b][i][j] = (i==j) ? 0.f : l;
    }
    if (lane < NC) {
      int n = lane;
      float sw2 = 0.f;
      #pragma unroll
      for (int m = 0; m < NC; ++m) sw2 += s_ww[b][m];
      s_prec2[b][n] = (1.f - sw2)*s_prec[b][n] + s_ww[b][n];
    }
    LDSFENCE();

    // K: commit prec, fwd/bwd on new link, read-content sims on new mem
    if (lane < NC) {
      int m = lane;
      s_prec[b][m] = s_prec2[b][m];
      float a = 0.f;
      #pragma unroll
      for (int n = 0; n < NC; ++n) a += s_rw[b][n]*s_link[b][m][n];
      s_fwd[b][m] = a;
    } else if (lane < 2*NC) {
      int m = lane - NC;
      float a = 0.f;
      #pragma unroll
      for (int n = 0; n < NC; ++n) a += s_rw[b][n]*s_link[b][n][m];
      s_bwd[b][m] = a;
    } else if (lane < 3*NC) {
      int n = lane - 2*NC;
      float dot=0.f, mn=0.f, kn=0.f;
      #pragma unroll
      for (int c = 0; c < CW; ++c) {
        float m = s_mem[b][n][c], k = s_rk[b][c];
        dot += k*m; mn += m*m; kn += k*k;
      }
      s_cr[b][n] = dot * rcpf(sqrtf(kn)*sqrtf(mn)+1e-6f) * s_sc[b][0];
    }
    LDSFENCE();

    // L: cr softmax + new read weights
    if (lane < NC) {
      int n = lane;
      float mx = -1e30f;
      #pragma unroll
      for (int m = 0; m < NC; ++m) mx = fmaxf(mx, s_cr[b][m]);
      float sm = 0.f;
      #pragma unroll
      for (int m = 0; m < NC; ++m) sm += __expf(s_cr[b][m]-mx);
      float cr = __expf(s_cr[b][n]-mx)*rcpf(sm);
      s_rw[b][n] = s_sc[b][5]*s_bwd[b][n] + s_sc[b][6]*cr + s_sc[b][7]*s_fwd[b][n];
    }
    LDSFENCE();

    // M: read vectors -> s_rv (fp32) + s_rvh (fp16)
    if (lane < CW) {
      int c = lane;
      float a = 0.f;
      #pragma unroll
      for (int n = 0; n < NC; ++n) a += s_rw[b][n]*s_mem[b][n][c];
      s_rv[b][c] = a;
      s_rvh[b][c] = (h1)a;
    }
  };

  for (int t = 0; t < NT; ++t) {
    // ===== R1: {waves 6,7: DNC(t-1) for batch 0/1} then all: g0p + g1p =====
    const int wv = tid >> 6;
    if (wv >= 6) {
      const int lane = tid & 63, b = wv - 6;
      float xv = 0.f;
      if (lane >= 32 && lane < 32+NIN && (t+1) < NT)
        xv = x[((size_t)(bg+b)*NT + (t+1))*NIN + (lane-32)];
      if (t > 0) {
        __builtin_amdgcn_s_setprio(1);
        dnc_tail(b, lane);
        __builtin_amdgcn_s_setprio(0);
      }
      if (lane >= 32 && lane < 32+NIN && (t+1) < NT)
        s_xbuf[(t+1)&1][b][lane-32] = (h1)xv;
    }
    unsigned lnd = 0;
    asm volatile("" : "+v"(lnd));   // launder: defeat LICM hoisting of invariant loads
    const float4* WS = (const float4*)((const char*)wsT + lnd);
    float4 u0 = WS[0*512+tid], u1 = WS[1*512+tid];
    float4 t0 = WS[2*512+tid], t1 = WS[3*512+tid];
    float r0a, r0b, g1a, g1b;
    {
      float a0=b0r, a1=b0r, a2=0.f, a3=0.f;
      const float4* Xa = (const float4*)&s_xbuf[t&1][0][0];
      const float4* Xb = (const float4*)&s_xbuf[t&1][1][0];
      LSTEP(A0,0,Xa,Xb) LSTEP(A1,1,Xa,Xb)
      const float4* Ha = (const float4*)s_h0h[0];
      const float4* Hb = (const float4*)s_h0h[1];
      LSTEP(B0,0,Ha,Hb)   LSTEP(B1,1,Ha,Hb)   LSTEP(B2,2,Ha,Hb)   LSTEP(B3,3,Ha,Hb)
      LSTEP(B4,4,Ha,Hb)   LSTEP(B5,5,Ha,Hb)   LSTEP(B6,6,Ha,Hb)   LSTEP(B7,7,Ha,Hb)
      LSTEP(B8,8,Ha,Hb)   LSTEP(B9,9,Ha,Hb)   LSTEP(B10,10,Ha,Hb) LSTEP(B11,11,Ha,Hb)
      LSTEP(B12,12,Ha,Hb) LSTEP(B13,13,Ha,Hb) LSTEP(B14,14,Ha,Hb) LSTEP(B15,15,Ha,Hb)
      r0a = a0+a2; r0b = a1+a3;
    }
    {
      float a0=0.f, a1=0.f, a2=0.f, a3=0.f;
      const float4* Ga = (const float4*)s_h1h[0];
      const float4* Gb = (const float4*)s_h1h[1];
      LSTEP(u0, 0,Ga,Gb) LSTEP(u1, 1,Ga,Gb)
      u0 = WS[ 4*512+tid]; u1 = WS[ 5*512+tid];
      LSTEP(t0, 2,Ga,Gb) LSTEP(t1, 3,Ga,Gb)
      t0 = WS[ 6*512+tid]; t1 = WS[ 7*512+tid];
      LSTEP(u0, 4,Ga,Gb) LSTEP(u1, 5,Ga,Gb)
      u0 = WS[ 8*512+tid]; u1 = WS[ 9*512+tid];
      LSTEP(t0, 6,Ga,Gb) LSTEP(t1, 7,Ga,Gb)
      t0 = WS[10*512+tid]; t1 = WS[11*512+tid];
      LSTEP(u0, 8,Ga,Gb) LSTEP(u1, 9,Ga,Gb)
      u0 = WS[12*512+tid]; u1 = WS[13*512+tid];
      LSTEP(t0,10,Ga,Gb) LSTEP(t1,11,Ga,Gb)
      t0 = WS[14*512+tid]; t1 = WS[15*512+tid];
      LSTEP(u0,12,Ga,Gb) LSTEP(u1,13,Ga,Gb)
      LSTEP(t0,14,Ga,Gb) LSTEP(t1,15,Ga,Gb)
      g1a = a0+a2; g1b = a1+a3;
    }
    __syncthreads();

    // ===== R2: finish g0 with rv, quad-exchange gates, LSTM0, write h0 =====
    {
      float a0=r0a, a1=r0b, a2=0.f, a3=0.f;
      const float4* Ra = (const float4*)&s_rvh[0][0];
      const float4* Rb = (const float4*)&s_rvh[1][0];
      LSTEP(A2,0,Ra,Rb) LSTEP(A3,1,Ra,Rb) LSTEP(A4,2,Ra,Rb)
      float gA = a0+a2, gB = a1+a3;
      float giA=bq0(gA), gfA=bq1(gA), ggA=bq2(gA), goA=bq3(gA);
      float giB=bq0(gB), gfB=bq1(gB), ggB=bq2(gB), goB=bq3(gB);
      float cA = sigf(gfA)*c0rA + sigf(giA)*tanhf_(ggA);
      float cB = sigf(gfB)*c0rB + sigf(giB)*tanhf_(ggB);
      c0rA = cA; c0rB = cB;
      float hA = sigf(goA)*tanhf_(cA);
      float hB = sigf(goB)*tanhf_(cB);
      if ((tid & 3) == 0) {
        int u = tid >> 2;
        s_h0h[0][u] = (h1)hA; s_h0h[1][u] = (h1)hB;
      }
    }
    __syncthreads();

    // ===== R3: g1 = g1p + b1 + Wih1·h0_new, quad-exchange, LSTM1+clip, write =====
    {
      float4 v0 = WS[16*512+tid], v1 = WS[17*512+tid];
      float a0 = g1a + b1r, a1 = g1b + b1r, a2=0.f, a3=0.f;
      const float4* Ha = (const float4*)s_h0h[0];
      const float4* Hb = (const float4*)s_h0h[1];
      { float4 w=s_wih1T[ 0][tid]; LSTEP(w, 0,Ha,Hb) }
      { float4 w=s_wih1T[ 1][tid]; LSTEP(w, 1,Ha,Hb) }
      { float4 w=s_wih1T[ 2][tid]; LSTEP(w, 2,Ha,Hb) }
      { float4 w=s_wih1T[ 3][tid]; LSTEP(w, 3,Ha,Hb) }
      { float4 w=s_wih1T[ 4][tid]; LSTEP(w, 4,Ha,Hb) }
      { float4 w=s_wih1T[ 5][tid]; LSTEP(w, 5,Ha,Hb) }
      { float4 w=s_wih1T[ 6][tid]; LSTEP(w, 6,Ha,Hb) }
      { float4 w=s_wih1T[ 7][tid]; LSTEP(w, 7,Ha,Hb) }
      { float4 w=s_wih1T[ 8][tid]; LSTEP(w, 8,Ha,Hb) }
      { float4 w=s_wih1T[ 9][tid]; LSTEP(w, 9,Ha,Hb) }
      { float4 w=s_wih1T[10][tid]; LSTEP(w,10,Ha,Hb) }
      { float4 w=s_wih1T[11][tid]; LSTEP(w,11,Ha,Hb) }
      { float4 w=s_wih1T[12][tid]; LSTEP(w,12,Ha,Hb) }
      { float4 w=s_wih1T[13][tid]; LSTEP(w,13,Ha,Hb) }
      LSTEP(v0,14,Ha,Hb) LSTEP(v1,15,Ha,Hb)
      float gA = a0+a2, gB = a1+a3;
      float giA=bq0(gA), gfA=bq1(gA), ggA=bq2(gA), goA=bq3(gA);
      float giB=bq0(gB), gfB=bq1(gB), ggB=bq2(gB), goB=bq3(gB);
      float cA = sigf(gfA)*c1rA + sigf(giA)*tanhf_(ggA);
      float cB = sigf(gfB)*c1rB + sigf(giB)*tanhf_(ggB);
      c1rA = cA; c1rB = cB;
      float hA = sigf(goA)*tanhf_(cA);
      float hB = sigf(goB)*tanhf_(cB);
      float clA = fminf(fmaxf(hA, -20.f), 20.f);
      float clB = fminf(fmaxf(hB, -20.f), 20.f);
      if ((tid & 3) == 0) {
        int u = tid >> 2;
        s_h1h[0][u] = (h1)hA;  s_h1h[1][u] = (h1)hB;
        s_ctrl[0][u] = clA;    s_ctrl[1][u] = clB;
        s_ctrlh[0][u] = (h1)clA; s_ctrlh[1][u] = (h1)clB;
      }
    }
    __syncthreads();

    // ===== R4: interface partials, 4 threads per row =====
    if (tid < 4*NIF) {
      int q = tid >> 2, c = tid & 3;
      float a0=0.f, a1=0.f, a2=0.f, a3=0.f;
      const float4* Ca = (const float4*)s_ctrlh[0];
      const float4* Cb = (const float4*)s_ctrlh[1];
      float4 w0 = s_wifT[(4*c+0)*89 + q];
      float4 w1 = s_wifT[(4*c+1)*89 + q];
      float4 w2 = s_wifT[(4*c+2)*89 + q];
      float4 w3 = s_wifT[(4*c+3)*89 + q];
      LSTEP(w0, 4*c+0, Ca, Cb) LSTEP(w1, 4*c+1, Ca, Cb)
      LSTEP(w2, 4*c+2, Ca, Cb) LSTEP(w3, 4*c+3, Ca, Cb)
      s_fp[q][2*c  ] = a0+a2;
      s_fp[q][2*c+1] = a1+a3;
    }
    __syncthreads();
  }

  // ---- final DNC for t = NT-1 ----
  if ((tid >> 6) >= 6) dnc_tail((tid >> 6) - 6, tid & 63);
  __syncthreads();

  // ---- epilogue: y_T = [ctrl, rv] @ Wout^T + bout ----
  if (tid < GB*NOUT) {
    int b = tid/NOUT, o = tid%NOUT;
    float a = bout[o];
    const float* Wr = Wout + o*(HID+CW);
    #pragma unroll 4
    for (int k = 0; k < HID; ++k) a += Wr[k]*s_ctrl[b][k];
    #pragma unroll
    for (int c = 0; c < CW; ++c) a += Wr[HID+c]*s_rv[b][c];
    out[(size_t)(bg+b)*NOUT + o] = a;
  }
}

extern "C" void kernel_launch(void* const* d_in, const int* in_sizes, int n_in,
                              void* d_out, int out_size, void* d_ws, size_t ws_size,
                              hipStream_t stream) {
  (void)in_sizes; (void)n_in; (void)out_size; (void)ws_size;
  const float* x    = (const float*)d_in[0];
  const float* Wih0 = (const float*)d_in[1];
  const float* Whh0 = (const float*)d_in[2];
  const float* b0   = (const float*)d_in[3];
  const float* Wih1 = (const float*)d_in[4];
  const float* Whh1 = (const float*)d_in[5];
  const float* b1   = (const float*)d_in[6];
  const float* Wif  = (const float*)d_in[7];
  const float* bif  = (const float*)d_in[8];
  const float* Wout = (const float*)d_in[9];
  const float* bout = (const float*)d_in[10];
  float* out = (float*)d_out;
  float4* ws = (float4*)d_ws;

  dnc_pack_kernel<<<dim3(36), dim3(256), 0, stream>>>(Wih1, Whh1, ws);
  dnc_quad_kernel<<<dim3(NB/GB), dim3(BLK), 0, stream>>>(
      x, Wih0, Whh0, b0, Wih1, Whh1, b1, Wif, bif, Wout, bout, ws, out);
}

// Round 10
// 6308.133 us; speedup vs baseline: 1.0190x; 1.0190x over previous
//
#include <hip/hip_runtime.h>
#include <math.h>

#define NT 512        // time steps
#define NB 512        // batch
#define HID 128
#define NIN 10
#define NC 10         // memory cells
#define CW 20         // cell width
#define NIF 88        // interface size
#define NOUT 10
#define BLK 512       // 8 waves -> VGPR grant 128; GB=1, 512 wgs -> 2 blocks/CU

typedef _Float16 h1;
typedef _Float16 h2 __attribute__((ext_vector_type(2)));

// ---- fast transcendentals (abs err ~1e-7, vs fp16 noise 5e-4) ----
__device__ __forceinline__ float rcpf(float x) { return __builtin_amdgcn_rcpf(x); }
__device__ __forceinline__ float sigf(float x) { return rcpf(1.0f + __expf(-x)); }
__device__ __forceinline__ float tanhf_(float x) {
  float xc = fminf(fmaxf(x, -15.f), 15.f);
  float e = __expf(2.f * xc);
  return (e - 1.f) * rcpf(e + 1.f);
}
// jax.nn.softplus == logaddexp(x, 0)
__device__ __forceinline__ float splus(float x) { return fmaxf(x, 0.0f) + __logf(1.f + __expf(-fabsf(x))); }

// fp16 pair dot with fp32 accumulate: v_dot2_f32_f16
__device__ __forceinline__ float dot2(h2 a, h2 b, float c) {
#if __has_builtin(__builtin_amdgcn_fdot2)
  return __builtin_amdgcn_fdot2(a, b, c, false);
#else
  c += (float)a.x * (float)b.x;
  c += (float)a.y * (float)b.y;
  return c;
#endif
}

// quad broadcast: every lane gets quad-lane k's value (BitMode: (lane&0x1C)|k)
__device__ __forceinline__ float bq0(float v) { return __builtin_bit_cast(float, __builtin_amdgcn_ds_swizzle(__builtin_bit_cast(int, v), 0x001C)); }
__device__ __forceinline__ float bq1(float v) { return __builtin_bit_cast(float, __builtin_amdgcn_ds_swizzle(__builtin_bit_cast(int, v), 0x003C)); }
__device__ __forceinline__ float bq2(float v) { return __builtin_bit_cast(float, __builtin_amdgcn_ds_swizzle(__builtin_bit_cast(int, v), 0x005C)); }
__device__ __forceinline__ float bq3(float v) { return __builtin_bit_cast(float, __builtin_amdgcn_ds_swizzle(__builtin_bit_cast(int, v), 0x007C)); }

// within-wave LDS ordering fence (no workgroup barrier)
#define LDSFENCE() do { asm volatile("s_waitcnt lgkmcnt(0)" ::: "memory"); \
                        __builtin_amdgcn_sched_barrier(0); } while (0)

#define BC(f) __builtin_bit_cast(h2, f)

// one float4 of packed fp16 weights (8 elems) x 8 fp16 activations, 1 batch
#define DOTS4(W, fa)                                       \
  a0 = dot2(BC((W).x), BC((fa).x), a0);                    \
  a2 = dot2(BC((W).y), BC((fa).y), a2);                    \
  a0 = dot2(BC((W).z), BC((fa).z), a0);                    \
  a2 = dot2(BC((W).w), BC((fa).w), a2);

#define LST(W, i, Pa) { float4 fa = (Pa)[i]; DOTS4(W, fa) }

__device__ __forceinline__ float4 pack8(const float* p) {
  h2 v0, v1, v2, v3;
  v0.x=(h1)p[0]; v0.y=(h1)p[1]; v1.x=(h1)p[2]; v1.y=(h1)p[3];
  v2.x=(h1)p[4]; v2.y=(h1)p[5]; v3.x=(h1)p[6]; v3.y=(h1)p[7];
  float4 r;
  r.x=__builtin_bit_cast(float,v0); r.y=__builtin_bit_cast(float,v1);
  r.z=__builtin_bit_cast(float,v2); r.w=__builtin_bit_cast(float,v3);
  return r;
}

// gate-interleaved row map: thread slot s owns gate-row R(s) (gate=s&3, unit=s>>2)
__device__ __host__ __forceinline__ int rowmap(int s) { return (s & 3) * 128 + (s >> 2); }

// ---- pack streamed weights (fp16, [chunk][slot], rows pre-remapped) into d_ws ----
// c 0..15 : Whh1 chunk c ; c 16..26 : Wih1 chunk (c-16+5)  (chunks 5..15)
__global__ __launch_bounds__(256) void dnc_pack_kernel(
    const float* __restrict__ Wih1, const float* __restrict__ Whh1, float4* __restrict__ ws)
{
  int i = blockIdx.x * 256 + threadIdx.x;   // 0..13823
  int s = i & 511, c = i >> 9;
  int R = rowmap(s);
  if (c < 16)      ws[i] = pack8(Whh1 + (size_t)R*HID + 8*c);
  else if (c < 27) ws[i] = pack8(Wih1 + (size_t)R*HID + 8*(c - 16 + 5));
}

__global__ __launch_bounds__(BLK)
void dnc_occ2_kernel(
    const float* __restrict__ x,
    const float* __restrict__ Wih0, const float* __restrict__ Whh0, const float* __restrict__ b0,
    const float* __restrict__ Wih1, const float* __restrict__ Whh1, const float* __restrict__ b1,
    const float* __restrict__ Wif,  const float* __restrict__ bif,
    const float* __restrict__ Wout, const float* __restrict__ bout,
    const float4* __restrict__ wsT,
    float* __restrict__ out)
{
  // ---- LDS (~69 KB -> 2 blocks/CU) ----
  __shared__ __align__(16) float4 s_wih1T[5][512];    // [chunk][slot]: Wih1 chunks 0-4, row R(slot)
  __shared__ __align__(16) float4 s_wifT[16*89];      // [chunk*89+row]: Wif, stride-89 padded
  __shared__ __align__(16) float s_fp[NIF][5];        // interface partials [row][c]
  __shared__ float s_bif[NIF];
  __shared__ __align__(16) h1   s_xbuf[2][16];        // double-buffered x_t (10 + pad6) fp16
  __shared__ __align__(16) h1   s_rvh[24];            // rv (20 + pad4) fp16
  __shared__ __align__(16) h1   s_h0h[HID];
  __shared__ __align__(16) h1   s_h1h[HID];
  __shared__ __align__(16) h1   s_ctrlh[HID];
  __shared__ __align__(16) float s_ctrl[HID];         // fp32 for epilogue
  __shared__ __align__(16) float s_mem[NC][CW];
  __shared__ float s_rk[CW], s_wk[CW], s_er[CW], s_wv[CW];
  __shared__ float s_mraw[3];
  __shared__ float s_sc[8];        // 0:rs 1:ws 2:fg 3:ga 4:gw 5:m0 6:m1 7:m2
  __shared__ float s_usage[NC], s_u[NC];
  __shared__ float s_prec[NC], s_prec2[NC];
  __shared__ float s_link[NC][NC];
  __shared__ float s_rw[NC], s_ww[NC];
  __shared__ float s_rv[CW];
  __shared__ float s_cw[NC], s_cr[NC], s_fwd[NC], s_bwd[NC];

  const int tid = threadIdx.x;
  const int bg  = blockIdx.x;       // ONE batch per workgroup
  const int R   = rowmap(tid);      // gate-row owned by this thread

  // ---- register weights: Wih0 padded row (5 f4) + Whh0 full row (16 f4) = 84 VGPRs ----
  float4 A0,A1,A2,A3,A4;
  float4 B0,B1,B2,B3,B4,B5,B6,B7,B8,B9,B10,B11,B12,B13,B14,B15;
  float b0r, b1r;
  {
    const float* p = Wih0 + (size_t)R * (NIN + CW);
    A0 = pack8(p);
    { h2 v0,z; v0.x=(h1)p[8]; v0.y=(h1)p[9]; z.x=(h1)0.f; z.y=(h1)0.f;
      float4 f; f.x=__builtin_bit_cast(float,v0); f.y=__builtin_bit_cast(float,z);
      f.z=f.y; f.w=f.y; A1=f; }
    A2 = pack8(p+10); A3 = pack8(p+18);
    { h2 v0,v1,z; v0.x=(h1)p[26]; v0.y=(h1)p[27]; v1.x=(h1)p[28]; v1.y=(h1)p[29];
      z.x=(h1)0.f; z.y=(h1)0.f;
      float4 f; f.x=__builtin_bit_cast(float,v0); f.y=__builtin_bit_cast(float,v1);
      f.z=__builtin_bit_cast(float,z); f.w=f.z; A4=f; }
    const float* q0 = Whh0 + (size_t)R*HID;
    B0 =pack8(q0);    B1 =pack8(q0+8);  B2 =pack8(q0+16);  B3 =pack8(q0+24);
    B4 =pack8(q0+32); B5 =pack8(q0+40); B6 =pack8(q0+48);  B7 =pack8(q0+56);
    B8 =pack8(q0+64); B9 =pack8(q0+72); B10=pack8(q0+80);  B11=pack8(q0+88);
    B12=pack8(q0+96); B13=pack8(q0+104);B14=pack8(q0+112); B15=pack8(q0+120);
    b0r = b0[R]; b1r = b1[R];
  }

  // ---- LDS weight staging (one-time, transposed, lane-contiguous, row-remapped) ----
  for (int idx = tid; idx < 5*512; idx += BLK) {
    int c = idx >> 9, s = idx & 511;
    s_wih1T[c][s] = pack8(Wih1 + (size_t)rowmap(s)*HID + 8*c);
  }
  for (int idx = tid; idx < 16*NIF; idx += BLK) {
    int j = idx / NIF, q = idx - j*NIF;
    s_wifT[j*89 + q] = pack8(Wif + (size_t)q*HID + 8*j);
  }
  if (tid < NIF) s_bif[tid] = bif[tid];

  // ---- zero-init state ----
  if (tid < HID) { int j=tid;
    s_h0h[j]=(h1)0.f; s_h1h[j]=(h1)0.f; s_ctrlh[j]=(h1)0.f; s_ctrl[j]=0.f; }
  if (tid < NC*CW) s_mem[tid/CW][tid%CW]=0.f;
  if (tid < NC*NC) s_link[tid/NC][tid%NC]=0.f;
  if (tid < NC) { s_usage[tid]=0.f; s_prec[tid]=0.f; s_rw[tid]=0.f; s_ww[tid]=0.f; }
  if (tid < CW) s_rv[tid]=0.f;
  if (tid < 24) s_rvh[tid]=(h1)0.f;
  if (tid < 32) { int d=tid>>4, i=tid&15;
    float v = 0.f;
    if (d == 0 && i < NIN) v = x[((size_t)bg*NT + 0)*NIN + i];
    s_xbuf[d][i] = (h1)v;
  }
  float c0r = 0.f, c1r = 0.f;   // replicated LSTM cell states (unit u = tid>>2)
  __syncthreads();

  // ---- full DNC tail for step t-1 (wave 7, 64 lanes), fences not barriers ----
  auto dnc_tail = [&](int lane) {
    // F-combine: xi = bif + sum of 4 partials, fused transforms
    #pragma unroll
    for (int q = lane; q < NIF; q += 64) {
      float a = s_bif[q] + s_fp[q][0] + s_fp[q][1] + s_fp[q][2] + s_fp[q][3];
      if      (q < 20)  s_rk[q]    = tanhf_(a);
      else if (q == 20) s_sc[0]    = splus(a);
      else if (q < 41)  s_wk[q-21] = tanhf_(a);
      else if (q == 41) s_sc[1]    = splus(a);
      else if (q < 62)  s_er[q-42] = sigf(a);
      else if (q < 82)  s_wv[q-62] = tanhf_(a);
      else if (q == 82) s_sc[2]    = sigf(a);
      else if (q == 83) s_sc[3]    = sigf(a);
      else if (q == 84) s_sc[4]    = sigf(a);
      else              s_mraw[q-85] = a;
    }
    LDSFENCE();

    // H: usage/psi + write-content sims + modes softmax
    if (lane < NC) {
      int n = lane;
      float fg = s_sc[2];
      float psi = 1.f - fg * s_rw[n];
      float u = s_usage[n], w = s_ww[n];
      u = (u + w - u*w) * psi;
      s_usage[n] = u;
      s_u[n] = 1e-6f + (1.0f - 1e-6f) * u;
      float dot=0.f, mn=0.f, kn=0.f;
      #pragma unroll
      for (int c = 0; c < CW; ++c) {
        float m = s_mem[n][c], k = s_wk[c];
        dot += k*m; mn += m*m; kn += k*k;
      }
      s_cw[n] = dot * rcpf(sqrtf(kn)*sqrtf(mn) + 1e-6f) * s_sc[1];
    } else if (lane == NC) {
      float m0=s_mraw[0], m1=s_mraw[1], m2=s_mraw[2];
      float mm = fmaxf(m0, fmaxf(m1, m2));
      float e0=__expf(m0-mm), e1=__expf(m1-mm), e2=__expf(m2-mm);
      float es = rcpf(e0+e1+e2);
      s_sc[5]=e0*es; s_sc[6]=e1*es; s_sc[7]=e2*es;
    }
    LDSFENCE();

    // I: cw softmax + rank-based allocation + new ww
    if (lane < NC) {
      int n = lane;
      float mx = -1e30f;
      #pragma unroll
      for (int m = 0; m < NC; ++m) mx = fmaxf(mx, s_cw[m]);
      float sm = 0.f;
      #pragma unroll
      for (int m = 0; m < NC; ++m) sm += __expf(s_cw[m]-mx);
      float cwv = __expf(s_cw[n]-mx) * rcpf(sm);
      float un = s_u[n];
      float excl = 1.f;
      #pragma unroll
      for (int m = 0; m < NC; ++m) {
        float um = s_u[m];
        bool before = (um < un) || (um == un && m < n);
        excl *= before ? um : 1.f;
      }
      float alloc = (1.f - un) * excl;
      float ga = s_sc[3], gw = s_sc[4];
      s_ww[n] = gw * (ga*alloc + (1.f-ga)*cwv);
    }
    LDSFENCE();

    // J: memory write + link update (old prec) + prec2
    #pragma unroll
    for (int e = lane; e < NC*CW; e += 64) {
      int rr = e/CW, c = e%CW;
      float w = s_ww[rr];
      s_mem[rr][c] = s_mem[rr][c] * (1.f - w*s_er[c]) + w*s_wv[c];
    }
    #pragma unroll
    for (int e = lane; e < NC*NC; e += 64) {
      int i = e/NC, j = e%NC;
      float wi = s_ww[i], wj = s_ww[j];
      float l = (1.f - wi - wj)*s_link[i][j] + wi*s_prec[j];
      s_link[i][j] = (i==j) ? 0.f : l;
    }
    if (lane < NC) {
      int n = lane;
      float sw2 = 0.f;
      #pragma unroll
      for (int m = 0; m < NC; ++m) sw2 += s_ww[m];
      s_prec2[n] = (1.f - sw2)*s_prec[n] + s_ww[n];
    }
    LDSFENCE();

    // K: commit prec, fwd/bwd on new link, read-content sims on new mem
    if (lane < NC) {
      int m = lane;
      s_prec[m] = s_prec2[m];
      float a = 0.f;
      #pragma unroll
      for (int n = 0; n < NC; ++n) a += s_rw[n]*s_link[m][n];
      s_fwd[m] = a;
    } else if (lane < 2*NC) {
      int m = lane - NC;
      float a = 0.f;
      #pragma unroll
      for (int n = 0; n < NC; ++n) a += s_rw[n]*s_link[n][m];
      s_bwd[m] = a;
    } else if (lane < 3*NC) {
      int n = lane - 2*NC;
      float dot=0.f, mn=0.f, kn=0.f;
      #pragma unroll
      for (int c = 0; c < CW; ++c) {
        float m = s_mem[n][c], k = s_rk[c];
        dot += k*m; mn += m*m; kn += k*k;
      }
      s_cr[n] = dot * rcpf(sqrtf(kn)*sqrtf(mn)+1e-6f) * s_sc[0];
    }
    LDSFENCE();

    // L: cr softmax + new read weights
    if (lane < NC) {
      int n = lane;
      float mx = -1e30f;
      #pragma unroll
      for (int m = 0; m < NC; ++m) mx = fmaxf(mx, s_cr[m]);
      float sm = 0.f;
      #pragma unroll
      for (int m = 0; m < NC; ++m) sm += __expf(s_cr[m]-mx);
      float cr = __expf(s_cr[n]-mx)*rcpf(sm);
      s_rw[n] = s_sc[5]*s_bwd[n] + s_sc[6]*cr + s_sc[7]*s_fwd[n];
    }
    LDSFENCE();

    // M: read vectors -> s_rv (fp32) + s_rvh (fp16)
    if (lane < CW) {
      int c = lane;
      float a = 0.f;
      #pragma unroll
      for (int n = 0; n < NC; ++n) a += s_rw[n]*s_mem[n][c];
      s_rv[c] = a;
      s_rvh[c] = (h1)a;
    }
  };

  for (int t = 0; t < NT; ++t) {
    // ===== R1: {wave 7: DNC(t-1)} ∥ {all: G0p (regs) + G1p (streamed Whh1)} =====
    if (tid >= 448) {
      const int lane = tid - 448;
      float xv = 0.f;
      if (lane >= 32 && lane < 32+NIN && (t+1) < NT)
        xv = x[((size_t)bg*NT + (t+1))*NIN + (lane-32)];
      if (t > 0) {
        __builtin_amdgcn_s_setprio(1);
        dnc_tail(lane);
        __builtin_amdgcn_s_setprio(0);
      }
      if (lane >= 32 && lane < 32+NIN && (t+1) < NT)
        s_xbuf[(t+1)&1][lane-32] = (h1)xv;
    }
    unsigned lnd = 0;
    asm volatile("" : "+v"(lnd));   // launder: defeat LICM hoisting of invariant loads
    const float4* WS = (const float4*)((const char*)wsT + lnd);
    float4 u0 = WS[0*512+tid], u1 = WS[1*512+tid];
    float4 u2 = WS[2*512+tid], u3 = WS[3*512+tid];
    float r0a, g1a;
    {
      float a0=b0r, a2=0.f;
      const float4* Xa = (const float4*)&s_xbuf[t&1][0];
      LST(A0,0,Xa) LST(A1,1,Xa)
      const float4* Ha = (const float4*)s_h0h;
      LST(B0,0,Ha)   LST(B1,1,Ha)   LST(B2,2,Ha)   LST(B3,3,Ha)
      LST(B4,4,Ha)   LST(B5,5,Ha)   LST(B6,6,Ha)   LST(B7,7,Ha)
      LST(B8,8,Ha)   LST(B9,9,Ha)   LST(B10,10,Ha) LST(B11,11,Ha)
      LST(B12,12,Ha) LST(B13,13,Ha) LST(B14,14,Ha) LST(B15,15,Ha)
      r0a = a0+a2;
    }
    {
      float a0=0.f, a2=0.f;
      const float4* Ga = (const float4*)s_h1h;
      LST(u0, 0,Ga) LST(u1, 1,Ga)
      u0 = WS[ 4*512+tid]; u1 = WS[ 5*512+tid];
      LST(u2, 2,Ga) LST(u3, 3,Ga)
      u2 = WS[ 6*512+tid]; u3 = WS[ 7*512+tid];
      LST(u0, 4,Ga) LST(u1, 5,Ga)
      u0 = WS[ 8*512+tid]; u1 = WS[ 9*512+tid];
      LST(u2, 6,Ga) LST(u3, 7,Ga)
      u2 = WS[10*512+tid]; u3 = WS[11*512+tid];
      LST(u0, 8,Ga) LST(u1, 9,Ga)
      u0 = WS[12*512+tid]; u1 = WS[13*512+tid];
      LST(u2,10,Ga) LST(u3,11,Ga)
      u2 = WS[14*512+tid]; u3 = WS[15*512+tid];
      LST(u0,12,Ga) LST(u1,13,Ga)
      LST(u2,14,Ga) LST(u3,15,Ga)
      g1a = a0+a2;
    }
    __syncthreads();

    // ===== R2: finish g0 with rv, quad-exchange gates, LSTM0, write h0 =====
    {
      float a0=r0a, a2=0.f;
      const float4* Ra = (const float4*)&s_rvh[0];
      LST(A2,0,Ra) LST(A3,1,Ra) LST(A4,2,Ra)
      float g = a0+a2;
      float gi=bq0(g), gf=bq1(g), gg=bq2(g), go=bq3(g);
      float c = sigf(gf)*c0r + sigf(gi)*tanhf_(gg);
      c0r = c;
      float h = sigf(go)*tanhf_(c);
      if ((tid & 3) == 0) s_h0h[tid >> 2] = (h1)h;
    }
    __syncthreads();

    // ===== R3: g1 = g1p + b1 + Wih1·h0_new (5 LDS + 11 streamed), LSTM1+clip =====
    {
      float4 v0 = WS[16*512+tid], v1 = WS[17*512+tid];
      float4 v2 = WS[18*512+tid], v3 = WS[19*512+tid];
      float a0 = g1a + b1r, a2=0.f;
      const float4* Ha = (const float4*)s_h0h;
      { float4 w=s_wih1T[0][tid]; LST(w,0,Ha) }
      { float4 w=s_wih1T[1][tid]; LST(w,1,Ha) }
      { float4 w=s_wih1T[2][tid]; LST(w,2,Ha) }
      { float4 w=s_wih1T[3][tid]; LST(w,3,Ha) }
      { float4 w=s_wih1T[4][tid]; LST(w,4,Ha) }
      LST(v0, 5,Ha) LST(v1, 6,Ha)
      v0 = WS[20*512+tid]; v1 = WS[21*512+tid];
      LST(v2, 7,Ha) LST(v3, 8,Ha)
      v2 = WS[22*512+tid]; v3 = WS[23*512+tid];
      LST(v0, 9,Ha) LST(v1,10,Ha)
      v0 = WS[24*512+tid]; v1 = WS[25*512+tid];
      LST(v2,11,Ha) LST(v3,12,Ha)
      v2 = WS[26*512+tid];
      LST(v0,13,Ha) LST(v1,14,Ha)
      LST(v2,15,Ha)
      float g = a0+a2;
      float gi=bq0(g), gf=bq1(g), gg=bq2(g), go=bq3(g);
      float c = sigf(gf)*c1r + sigf(gi)*tanhf_(gg);
      c1r = c;
      float h = sigf(go)*tanhf_(c);
      float cl = fminf(fmaxf(h, -20.f), 20.f);
      if ((tid & 3) == 0) {
        int u = tid >> 2;
        s_h1h[u] = (h1)h;
        s_ctrl[u] = cl;
        s_ctrlh[u] = (h1)cl;
      }
    }
    __syncthreads();

    // ===== R4: interface partials, 4 threads per row =====
    if (tid < 4*NIF) {
      int q = tid >> 2, c = tid & 3;
      float a0=0.f, a2=0.f;
      const float4* Ca = (const float4*)s_ctrlh;
      float4 w0 = s_wifT[(4*c+0)*89 + q];
      float4 w1 = s_wifT[(4*c+1)*89 + q];
      float4 w2 = s_wifT[(4*c+2)*89 + q];
      float4 w3 = s_wifT[(4*c+3)*89 + q];
      LST(w0, 4*c+0, Ca) LST(w1, 4*c+1, Ca)
      LST(w2, 4*c+2, Ca) LST(w3, 4*c+3, Ca)
      s_fp[q][c] = a0+a2;
    }
    __syncthreads();
  }

  // ---- final DNC for t = NT-1 ----
  if (tid >= 448) dnc_tail(tid - 448);
  __syncthreads();

  // ---- epilogue: y_T = [ctrl, rv] @ Wout^T + bout ----
  if (tid < NOUT) {
    int o = tid;
    float a = bout[o];
    const float* Wr = Wout + o*(HID+CW);
    #pragma unroll 4
    for (int k = 0; k < HID; ++k) a += Wr[k]*s_ctrl[k];
    #pragma unroll
    for (int c = 0; c < CW; ++c) a += Wr[HID+c]*s_rv[c];
    out[(size_t)bg*NOUT + o] = a;
  }
}

extern "C" void kernel_launch(void* const* d_in, const int* in_sizes, int n_in,
                              void* d_out, int out_size, void* d_ws, size_t ws_size,
                              hipStream_t stream) {
  (void)in_sizes; (void)n_in; (void)out_size; (void)ws_size;
  const float* x    = (const float*)d_in[0];
  const float* Wih0 = (const float*)d_in[1];
  const float* Whh0 = (const float*)d_in[2];
  const float* b0   = (const float*)d_in[3];
  const float* Wih1 = (const float*)d_in[4];
  const float* Whh1 = (const float*)d_in[5];
  const float* b1   = (const float*)d_in[6];
  const float* Wif  = (const float*)d_in[7];
  const float* bif  = (const float*)d_in[8];
  const float* Wout = (const float*)d_in[9];
  const float* bout = (const float*)d_in[10];
  float* out = (float*)d_out;
  float4* ws = (float4*)d_ws;

  dnc_pack_kernel<<<dim3(54), dim3(256), 0, stream>>>(Wih1, Whh1, ws);
  dnc_occ2_kernel<<<dim3(NB), dim3(BLK), 0, stream>>>(
      x, Wih0, Whh0, b0, Wih1, Whh1, b1, Wif, bif, Wout, bout, ws, out);
}

// Round 11
// 5952.801 us; speedup vs baseline: 1.0798x; 1.0597x over previous
//
#include <hip/hip_runtime.h>
#include <math.h>

#define NT 512        // time steps
#define NB 512        // batch
#define HID 128
#define NIN 10
#define NC 10         // memory cells
#define CW 20         // cell width
#define NIF 88        // interface size
#define NOUT 10
#define BLK 512       // 8 waves -> VGPR grant 128; GB=1, 512 wgs -> target 2 blocks/CU

typedef _Float16 h1;
typedef _Float16 h2 __attribute__((ext_vector_type(2)));

// ---- fast transcendentals (abs err ~1e-7, vs fp16 noise 5e-4) ----
__device__ __forceinline__ float rcpf(float x) { return __builtin_amdgcn_rcpf(x); }
__device__ __forceinline__ float sigf(float x) { return rcpf(1.0f + __expf(-x)); }
__device__ __forceinline__ float tanhf_(float x) {
  float xc = fminf(fmaxf(x, -15.f), 15.f);
  float e = __expf(2.f * xc);
  return (e - 1.f) * rcpf(e + 1.f);
}
// jax.nn.softplus == logaddexp(x, 0)
__device__ __forceinline__ float splus(float x) { return fmaxf(x, 0.0f) + __logf(1.f + __expf(-fabsf(x))); }

// fp16 pair dot with fp32 accumulate: v_dot2_f32_f16
__device__ __forceinline__ float dot2(h2 a, h2 b, float c) {
#if __has_builtin(__builtin_amdgcn_fdot2)
  return __builtin_amdgcn_fdot2(a, b, c, false);
#else
  c += (float)a.x * (float)b.x;
  c += (float)a.y * (float)b.y;
  return c;
#endif
}

// quad broadcast: every lane gets quad-lane k's value (BitMode: (lane&0x1C)|k)
__device__ __forceinline__ float bq0(float v) { return __builtin_bit_cast(float, __builtin_amdgcn_ds_swizzle(__builtin_bit_cast(int, v), 0x001C)); }
__device__ __forceinline__ float bq1(float v) { return __builtin_bit_cast(float, __builtin_amdgcn_ds_swizzle(__builtin_bit_cast(int, v), 0x003C)); }
__device__ __forceinline__ float bq2(float v) { return __builtin_bit_cast(float, __builtin_amdgcn_ds_swizzle(__builtin_bit_cast(int, v), 0x005C)); }
__device__ __forceinline__ float bq3(float v) { return __builtin_bit_cast(float, __builtin_amdgcn_ds_swizzle(__builtin_bit_cast(int, v), 0x007C)); }

// within-wave LDS ordering fence (no workgroup barrier)
#define LDSFENCE() do { asm volatile("s_waitcnt lgkmcnt(0)" ::: "memory"); \
                        __builtin_amdgcn_sched_barrier(0); } while (0)

#define BC(f) __builtin_bit_cast(h2, f)

// one float4 of packed fp16 weights (8 elems) x 8 fp16 activations, 1 batch
#define DOTS4(W, fa)                                       \
  a0 = dot2(BC((W).x), BC((fa).x), a0);                    \
  a2 = dot2(BC((W).y), BC((fa).y), a2);                    \
  a0 = dot2(BC((W).z), BC((fa).z), a0);                    \
  a2 = dot2(BC((W).w), BC((fa).w), a2);

#define LST(W, i, Pa) { float4 fa = (Pa)[i]; DOTS4(W, fa) }

__device__ __forceinline__ float4 pack8(const float* p) {
  h2 v0, v1, v2, v3;
  v0.x=(h1)p[0]; v0.y=(h1)p[1]; v1.x=(h1)p[2]; v1.y=(h1)p[3];
  v2.x=(h1)p[4]; v2.y=(h1)p[5]; v3.x=(h1)p[6]; v3.y=(h1)p[7];
  float4 r;
  r.x=__builtin_bit_cast(float,v0); r.y=__builtin_bit_cast(float,v1);
  r.z=__builtin_bit_cast(float,v2); r.w=__builtin_bit_cast(float,v3);
  return r;
}

// gate-interleaved row map: thread slot s owns gate-row R(s) (gate=s&3, unit=s>>2)
__device__ __host__ __forceinline__ int rowmap(int s) { return (s & 3) * 128 + (s >> 2); }

// ---- pack streamed weights (fp16, [chunk][slot], rows pre-remapped) into d_ws ----
// c 0..15 : Whh1 chunk c ; c 16..28 : Wih1 chunk (c-16+3)  (chunks 3..15)
__global__ __launch_bounds__(256) void dnc_pack_kernel(
    const float* __restrict__ Wih1, const float* __restrict__ Whh1, float4* __restrict__ ws)
{
  int i = blockIdx.x * 256 + threadIdx.x;   // 0..14847
  int s = i & 511, c = i >> 9;
  int R = rowmap(s);
  if (c < 16)      ws[i] = pack8(Whh1 + (size_t)R*HID + 8*c);
  else if (c < 29) ws[i] = pack8(Wih1 + (size_t)R*HID + 8*(c - 16 + 3));
}

__global__ __launch_bounds__(BLK)
void dnc_occ2b_kernel(
    const float* __restrict__ x,
    const float* __restrict__ Wih0, const float* __restrict__ Whh0, const float* __restrict__ b0,
    const float* __restrict__ Wih1, const float* __restrict__ Whh1, const float* __restrict__ b1,
    const float* __restrict__ Wif,  const float* __restrict__ bif,
    const float* __restrict__ Wout, const float* __restrict__ bout,
    const float4* __restrict__ wsT,
    float* __restrict__ out)
{
  // ---- LDS (~53 KB -> 2 blocks/CU under both 128KB-pool and 80KB-granule hypotheses) ----
  __shared__ __align__(16) float4 s_wih1T[3][512];    // [chunk][slot]: Wih1 chunks 0-2, row R(slot)
  __shared__ __align__(16) float4 s_wifT[16*89];      // [chunk*89+row]: Wif, stride-89 padded
  __shared__ __align__(16) float s_fp[NIF][5];        // interface partials [row][c]
  __shared__ float s_bif[NIF];
  __shared__ __align__(16) h1   s_xbuf[2][16];        // double-buffered x_t (10 + pad6) fp16
  __shared__ __align__(16) h1   s_rvh[24];            // rv (20 + pad4) fp16
  __shared__ __align__(16) h1   s_h0h[HID];
  __shared__ __align__(16) h1   s_h1h[HID];
  __shared__ __align__(16) h1   s_ctrlh[HID];
  __shared__ __align__(16) float s_ctrl[HID];         // fp32 for epilogue
  __shared__ __align__(16) float s_mem[NC][CW];
  __shared__ float s_rk[CW], s_wk[CW], s_er[CW], s_wv[CW];
  __shared__ float s_mraw[3];
  __shared__ float s_sc[8];        // 0:rs 1:ws 2:fg 3:ga 4:gw 5:m0 6:m1 7:m2
  __shared__ float s_usage[NC], s_u[NC];
  __shared__ float s_prec[NC], s_prec2[NC];
  __shared__ float s_link[NC][NC];
  __shared__ float s_rw[NC], s_ww[NC];
  __shared__ float s_rv[CW];
  __shared__ float s_cw[NC], s_cr[NC], s_fwd[NC], s_bwd[NC];

  const int tid = threadIdx.x;
  const int bg  = blockIdx.x;       // ONE batch per workgroup
  const int R   = rowmap(tid);      // gate-row owned by this thread

  // ---- register weights: Wih0 padded row (5 f4) + Whh0 full row (16 f4) = 84 VGPRs ----
  float4 A0,A1,A2,A3,A4;
  float4 B0,B1,B2,B3,B4,B5,B6,B7,B8,B9,B10,B11,B12,B13,B14,B15;
  float b0r, b1r;
  {
    const float* p = Wih0 + (size_t)R * (NIN + CW);
    A0 = pack8(p);
    { h2 v0,z; v0.x=(h1)p[8]; v0.y=(h1)p[9]; z.x=(h1)0.f; z.y=(h1)0.f;
      float4 f; f.x=__builtin_bit_cast(float,v0); f.y=__builtin_bit_cast(float,z);
      f.z=f.y; f.w=f.y; A1=f; }
    A2 = pack8(p+10); A3 = pack8(p+18);
    { h2 v0,v1,z; v0.x=(h1)p[26]; v0.y=(h1)p[27]; v1.x=(h1)p[28]; v1.y=(h1)p[29];
      z.x=(h1)0.f; z.y=(h1)0.f;
      float4 f; f.x=__builtin_bit_cast(float,v0); f.y=__builtin_bit_cast(float,v1);
      f.z=__builtin_bit_cast(float,z); f.w=f.z; A4=f; }
    const float* q0 = Whh0 + (size_t)R*HID;
    B0 =pack8(q0);    B1 =pack8(q0+8);  B2 =pack8(q0+16);  B3 =pack8(q0+24);
    B4 =pack8(q0+32); B5 =pack8(q0+40); B6 =pack8(q0+48);  B7 =pack8(q0+56);
    B8 =pack8(q0+64); B9 =pack8(q0+72); B10=pack8(q0+80);  B11=pack8(q0+88);
    B12=pack8(q0+96); B13=pack8(q0+104);B14=pack8(q0+112); B15=pack8(q0+120);
    b0r = b0[R]; b1r = b1[R];
  }

  // ---- LDS weight staging (one-time, transposed, lane-contiguous, row-remapped) ----
  for (int idx = tid; idx < 3*512; idx += BLK) {
    int c = idx >> 9, s = idx & 511;
    s_wih1T[c][s] = pack8(Wih1 + (size_t)rowmap(s)*HID + 8*c);
  }
  for (int idx = tid; idx < 16*NIF; idx += BLK) {
    int j = idx / NIF, q = idx - j*NIF;
    s_wifT[j*89 + q] = pack8(Wif + (size_t)q*HID + 8*j);
  }
  if (tid < NIF) s_bif[tid] = bif[tid];

  // ---- zero-init state ----
  if (tid < HID) { int j=tid;
    s_h0h[j]=(h1)0.f; s_h1h[j]=(h1)0.f; s_ctrlh[j]=(h1)0.f; s_ctrl[j]=0.f; }
  if (tid < NC*CW) s_mem[tid/CW][tid%CW]=0.f;
  if (tid < NC*NC) s_link[tid/NC][tid%NC]=0.f;
  if (tid < NC) { s_usage[tid]=0.f; s_prec[tid]=0.f; s_rw[tid]=0.f; s_ww[tid]=0.f; }
  if (tid < CW) s_rv[tid]=0.f;
  if (tid < 24) s_rvh[tid]=(h1)0.f;
  if (tid < 32) { int d=tid>>4, i=tid&15;
    float v = 0.f;
    if (d == 0 && i < NIN) v = x[((size_t)bg*NT + 0)*NIN + i];
    s_xbuf[d][i] = (h1)v;
  }
  float c0r = 0.f, c1r = 0.f;   // replicated LSTM cell states (unit u = tid>>2)
  __syncthreads();

  // ---- full DNC tail for step t-1 (wave 7, 64 lanes), fences not barriers ----
  auto dnc_tail = [&](int lane) {
    // F-combine: xi = bif + sum of 4 partials, fused transforms
    #pragma unroll
    for (int q = lane; q < NIF; q += 64) {
      float a = s_bif[q] + s_fp[q][0] + s_fp[q][1] + s_fp[q][2] + s_fp[q][3];
      if      (q < 20)  s_rk[q]    = tanhf_(a);
      else if (q == 20) s_sc[0]    = splus(a);
      else if (q < 41)  s_wk[q-21] = tanhf_(a);
      else if (q == 41) s_sc[1]    = splus(a);
      else if (q < 62)  s_er[q-42] = sigf(a);
      else if (q < 82)  s_wv[q-62] = tanhf_(a);
      else if (q == 82) s_sc[2]    = sigf(a);
      else if (q == 83) s_sc[3]    = sigf(a);
      else if (q == 84) s_sc[4]    = sigf(a);
      else              s_mraw[q-85] = a;
    }
    LDSFENCE();

    // H: usage/psi + write-content sims + modes softmax
    if (lane < NC) {
      int n = lane;
      float fg = s_sc[2];
      float psi = 1.f - fg * s_rw[n];
      float u = s_usage[n], w = s_ww[n];
      u = (u + w - u*w) * psi;
      s_usage[n] = u;
      s_u[n] = 1e-6f + (1.0f - 1e-6f) * u;
      float dot=0.f, mn=0.f, kn=0.f;
      #pragma unroll
      for (int c = 0; c < CW; ++c) {
        float m = s_mem[n][c], k = s_wk[c];
        dot += k*m; mn += m*m; kn += k*k;
      }
      s_cw[n] = dot * rcpf(sqrtf(kn)*sqrtf(mn) + 1e-6f) * s_sc[1];
    } else if (lane == NC) {
      float m0=s_mraw[0], m1=s_mraw[1], m2=s_mraw[2];
      float mm = fmaxf(m0, fmaxf(m1, m2));
      float e0=__expf(m0-mm), e1=__expf(m1-mm), e2=__expf(m2-mm);
      float es = rcpf(e0+e1+e2);
      s_sc[5]=e0*es; s_sc[6]=e1*es; s_sc[7]=e2*es;
    }
    LDSFENCE();

    // I: cw softmax + rank-based allocation + new ww
    if (lane < NC) {
      int n = lane;
      float mx = -1e30f;
      #pragma unroll
      for (int m = 0; m < NC; ++m) mx = fmaxf(mx, s_cw[m]);
      float sm = 0.f;
      #pragma unroll
      for (int m = 0; m < NC; ++m) sm += __expf(s_cw[m]-mx);
      float cwv = __expf(s_cw[n]-mx) * rcpf(sm);
      float un = s_u[n];
      float excl = 1.f;
      #pragma unroll
      for (int m = 0; m < NC; ++m) {
        float um = s_u[m];
        bool before = (um < un) || (um == un && m < n);
        excl *= before ? um : 1.f;
      }
      float alloc = (1.f - un) * excl;
      float ga = s_sc[3], gw = s_sc[4];
      s_ww[n] = gw * (ga*alloc + (1.f-ga)*cwv);
    }
    LDSFENCE();

    // J: memory write + link update (old prec) + prec2
    #pragma unroll
    for (int e = lane; e < NC*CW; e += 64) {
      int rr = e/CW, c = e%CW;
      float w = s_ww[rr];
      s_mem[rr][c] = s_mem[rr][c] * (1.f - w*s_er[c]) + w*s_wv[c];
    }
    #pragma unroll
    for (int e = lane; e < NC*NC; e += 64) {
      int i = e/NC, j = e%NC;
      float wi = s_ww[i], wj = s_ww[j];
      float l = (1.f - wi - wj)*s_link[i][j] + wi*s_prec[j];
      s_link[i][j] = (i==j) ? 0.f : l;
    }
    if (lane < NC) {
      int n = lane;
      float sw2 = 0.f;
      #pragma unroll
      for (int m = 0; m < NC; ++m) sw2 += s_ww[m];
      s_prec2[n] = (1.f - sw2)*s_prec[n] + s_ww[n];
    }
    LDSFENCE();

    // K: commit prec, fwd/bwd on new link, read-content sims on new mem
    if (lane < NC) {
      int m = lane;
      s_prec[m] = s_prec2[m];
      float a = 0.f;
      #pragma unroll
      for (int n = 0; n < NC; ++n) a += s_rw[n]*s_link[m][n];
      s_fwd[m] = a;
    } else if (lane < 2*NC) {
      int m = lane - NC;
      float a = 0.f;
      #pragma unroll
      for (int n = 0; n < NC; ++n) a += s_rw[n]*s_link[n][m];
      s_bwd[m] = a;
    } else if (lane < 3*NC) {
      int n = lane - 2*NC;
      float dot=0.f, mn=0.f, kn=0.f;
      #pragma unroll
      for (int c = 0; c < CW; ++c) {
        float m = s_mem[n][c], k = s_rk[c];
        dot += k*m; mn += m*m; kn += k*k;
      }
      s_cr[n] = dot * rcpf(sqrtf(kn)*sqrtf(mn)+1e-6f) * s_sc[0];
    }
    LDSFENCE();

    // L: cr softmax + new read weights
    if (lane < NC) {
      int n = lane;
      float mx = -1e30f;
      #pragma unroll
      for (int m = 0; m < NC; ++m) mx = fmaxf(mx, s_cr[m]);
      float sm = 0.f;
      #pragma unroll
      for (int m = 0; m < NC; ++m) sm += __expf(s_cr[m]-mx);
      float cr = __expf(s_cr[n]-mx)*rcpf(sm);
      s_rw[n] = s_sc[5]*s_bwd[n] + s_sc[6]*cr + s_sc[7]*s_fwd[n];
    }
    LDSFENCE();

    // M: read vectors -> s_rv (fp32) + s_rvh (fp16)
    if (lane < CW) {
      int c = lane;
      float a = 0.f;
      #pragma unroll
      for (int n = 0; n < NC; ++n) a += s_rw[n]*s_mem[n][c];
      s_rv[c] = a;
      s_rvh[c] = (h1)a;
    }
  };

  for (int t = 0; t < NT; ++t) {
    // ===== R1: {wave 7: DNC(t-1)} ∥ {all: G0p (regs) + G1p (streamed Whh1)} =====
    if (tid >= 448) {
      const int lane = tid - 448;
      float xv = 0.f;
      if (lane >= 32 && lane < 32+NIN && (t+1) < NT)
        xv = x[((size_t)bg*NT + (t+1))*NIN + (lane-32)];
      if (t > 0) {
        __builtin_amdgcn_s_setprio(1);
        dnc_tail(lane);
        __builtin_amdgcn_s_setprio(0);
      }
      if (lane >= 32 && lane < 32+NIN && (t+1) < NT)
        s_xbuf[(t+1)&1][lane-32] = (h1)xv;
    }
    unsigned lnd = 0;
    asm volatile("" : "+v"(lnd));   // launder: defeat LICM hoisting of invariant loads
    const float4* WS = (const float4*)((const char*)wsT + lnd);
    float4 u0 = WS[0*512+tid], u1 = WS[1*512+tid];
    float4 u2 = WS[2*512+tid], u3 = WS[3*512+tid];
    float r0a, g1a;
    {
      float a0=b0r, a2=0.f;
      const float4* Xa = (const float4*)&s_xbuf[t&1][0];
      LST(A0,0,Xa) LST(A1,1,Xa)
      const float4* Ha = (const float4*)s_h0h;
      LST(B0,0,Ha)   LST(B1,1,Ha)   LST(B2,2,Ha)   LST(B3,3,Ha)
      LST(B4,4,Ha)   LST(B5,5,Ha)   LST(B6,6,Ha)   LST(B7,7,Ha)
      LST(B8,8,Ha)   LST(B9,9,Ha)   LST(B10,10,Ha) LST(B11,11,Ha)
      LST(B12,12,Ha) LST(B13,13,Ha) LST(B14,14,Ha) LST(B15,15,Ha)
      r0a = a0+a2;
    }
    {
      float a0=0.f, a2=0.f;
      const float4* Ga = (const float4*)s_h1h;
      LST(u0, 0,Ga) LST(u1, 1,Ga)
      u0 = WS[ 4*512+tid]; u1 = WS[ 5*512+tid];
      LST(u2, 2,Ga) LST(u3, 3,Ga)
      u2 = WS[ 6*512+tid]; u3 = WS[ 7*512+tid];
      LST(u0, 4,Ga) LST(u1, 5,Ga)
      u0 = WS[ 8*512+tid]; u1 = WS[ 9*512+tid];
      LST(u2, 6,Ga) LST(u3, 7,Ga)
      u2 = WS[10*512+tid]; u3 = WS[11*512+tid];
      LST(u0, 8,Ga) LST(u1, 9,Ga)
      u0 = WS[12*512+tid]; u1 = WS[13*512+tid];
      LST(u2,10,Ga) LST(u3,11,Ga)
      u2 = WS[14*512+tid]; u3 = WS[15*512+tid];
      LST(u0,12,Ga) LST(u1,13,Ga)
      LST(u2,14,Ga) LST(u3,15,Ga)
      g1a = a0+a2;
    }
    __syncthreads();

    // ===== R2: finish g0 with rv, quad-exchange gates, LSTM0, write h0 =====
    {
      float a0=r0a, a2=0.f;
      const float4* Ra = (const float4*)&s_rvh[0];
      LST(A2,0,Ra) LST(A3,1,Ra) LST(A4,2,Ra)
      float g = a0+a2;
      float gi=bq0(g), gf=bq1(g), gg=bq2(g), go=bq3(g);
      float c = sigf(gf)*c0r + sigf(gi)*tanhf_(gg);
      c0r = c;
      float h = sigf(go)*tanhf_(c);
      if ((tid & 3) == 0) s_h0h[tid >> 2] = (h1)h;
    }
    __syncthreads();

    // ===== R3: g1 = g1p + b1 + Wih1·h0_new (3 LDS + 13 streamed), LSTM1+clip =====
    {
      float4 v0 = WS[16*512+tid], v1 = WS[17*512+tid];
      float4 v2 = WS[18*512+tid], v3 = WS[19*512+tid];
      float a0 = g1a + b1r, a2=0.f;
      const float4* Ha = (const float4*)s_h0h;
      { float4 w=s_wih1T[0][tid]; LST(w,0,Ha) }
      { float4 w=s_wih1T[1][tid]; LST(w,1,Ha) }
      { float4 w=s_wih1T[2][tid]; LST(w,2,Ha) }
      LST(v0, 3,Ha) LST(v1, 4,Ha)
      v0 = WS[20*512+tid]; v1 = WS[21*512+tid];
      LST(v2, 5,Ha) LST(v3, 6,Ha)
      v2 = WS[22*512+tid]; v3 = WS[23*512+tid];
      LST(v0, 7,Ha) LST(v1, 8,Ha)
      v0 = WS[24*512+tid]; v1 = WS[25*512+tid];
      LST(v2, 9,Ha) LST(v3,10,Ha)
      v2 = WS[26*512+tid]; v3 = WS[27*512+tid];
      LST(v0,11,Ha) LST(v1,12,Ha)
      v0 = WS[28*512+tid];
      LST(v2,13,Ha) LST(v3,14,Ha)
      LST(v0,15,Ha)
      float g = a0+a2;
      float gi=bq0(g), gf=bq1(g), gg=bq2(g), go=bq3(g);
      float c = sigf(gf)*c1r + sigf(gi)*tanhf_(gg);
      c1r = c;
      float h = sigf(go)*tanhf_(c);
      float cl = fminf(fmaxf(h, -20.f), 20.f);
      if ((tid & 3) == 0) {
        int u = tid >> 2;
        s_h1h[u] = (h1)h;
        s_ctrl[u] = cl;
        s_ctrlh[u] = (h1)cl;
      }
    }
    __syncthreads();

    // ===== R4: interface partials, 4 threads per row =====
    if (tid < 4*NIF) {
      int q = tid >> 2, c = tid & 3;
      float a0=0.f, a2=0.f;
      const float4* Ca = (const float4*)s_ctrlh;
      float4 w0 = s_wifT[(4*c+0)*89 + q];
      float4 w1 = s_wifT[(4*c+1)*89 + q];
      float4 w2 = s_wifT[(4*c+2)*89 + q];
      float4 w3 = s_wifT[(4*c+3)*89 + q];
      LST(w0, 4*c+0, Ca) LST(w1, 4*c+1, Ca)
      LST(w2, 4*c+2, Ca) LST(w3, 4*c+3, Ca)
      s_fp[q][c] = a0+a2;
    }
    __syncthreads();
  }

  // ---- final DNC for t = NT-1 ----
  if (tid >= 448) dnc_tail(tid - 448);
  __syncthreads();

  // ---- epilogue: y_T = [ctrl, rv] @ Wout^T + bout ----
  if (tid < NOUT) {
    int o = tid;
    float a = bout[o];
    const float* Wr = Wout + o*(HID+CW);
    #pragma unroll 4
    for (int k = 0; k < HID; ++k) a += Wr[k]*s_ctrl[k];
    #pragma unroll
    for (int c = 0; c < CW; ++c) a += Wr[HID+c]*s_rv[c];
    out[(size_t)bg*NOUT + o] = a;
  }
}

extern "C" void kernel_launch(void* const* d_in, const int* in_sizes, int n_in,
                              void* d_out, int out_size, void* d_ws, size_t ws_size,
                              hipStream_t stream) {
  (void)in_sizes; (void)n_in; (void)out_size; (void)ws_size;
  const float* x    = (const float*)d_in[0];
  const float* Wih0 = (const float*)d_in[1];
  const float* Whh0 = (const float*)d_in[2];
  const float* b0   = (const float*)d_in[3];
  const float* Wih1 = (const float*)d_in[4];
  const float* Whh1 = (const float*)d_in[5];
  const float* b1   = (const float*)d_in[6];
  const float* Wif  = (const float*)d_in[7];
  const float* bif  = (const float*)d_in[8];
  const float* Wout = (const float*)d_in[9];
  const float* bout = (const float*)d_in[10];
  float* out = (float*)d_out;
  float4* ws = (float4*)d_ws;

  dnc_pack_kernel<<<dim3(58), dim3(256), 0, stream>>>(Wih1, Whh1, ws);
  dnc_occ2b_kernel<<<dim3(NB), dim3(BLK), 0, stream>>>(
      x, Wih0, Whh0, b0, Wih1, Whh1, b1, Wif, bif, Wout, bout, ws, out);
}

// Round 12
// 5543.262 us; speedup vs baseline: 1.1595x; 1.0739x over previous
//
#include <hip/hip_runtime.h>
#include <math.h>

#define NT 512        // time steps
#define NB 512        // batch
#define HID 128
#define NIN 10
#define NC 10         // memory cells
#define CW 20         // cell width
#define NIF 88        // interface size
#define NOUT 10
#define GB 16         // batches per workgroup = MFMA M dim
#define BLK 512       // 8 waves
#define NWG (NB/GB)   // 32 workgroups

typedef _Float16 h1;
typedef _Float16 h8 __attribute__((ext_vector_type(8)));
typedef float f32x4 __attribute__((ext_vector_type(4)));

// ---- fast transcendentals (abs err ~1e-7 vs fp16 noise 5e-4) ----
__device__ __forceinline__ float rcpf(float x) { return __builtin_amdgcn_rcpf(x); }
__device__ __forceinline__ float sigf(float x) { return rcpf(1.0f + __expf(-x)); }
__device__ __forceinline__ float tanhf_(float x) {
  float xc = fminf(fmaxf(x, -15.f), 15.f);
  float e = __expf(2.f * xc);
  return (e - 1.f) * rcpf(e + 1.f);
}
__device__ __forceinline__ float splus(float x) { return fmaxf(x, 0.0f) + __logf(1.f + __expf(-fabsf(x))); }

// quad broadcast: every lane gets quad-lane k's value (BitMode: (lane&0x1C)|k)
__device__ __forceinline__ float bq0(float v) { return __builtin_bit_cast(float, __builtin_amdgcn_ds_swizzle(__builtin_bit_cast(int, v), 0x001C)); }
__device__ __forceinline__ float bq1(float v) { return __builtin_bit_cast(float, __builtin_amdgcn_ds_swizzle(__builtin_bit_cast(int, v), 0x003C)); }
__device__ __forceinline__ float bq2(float v) { return __builtin_bit_cast(float, __builtin_amdgcn_ds_swizzle(__builtin_bit_cast(int, v), 0x005C)); }
__device__ __forceinline__ float bq3(float v) { return __builtin_bit_cast(float, __builtin_amdgcn_ds_swizzle(__builtin_bit_cast(int, v), 0x007C)); }

__device__ __forceinline__ f32x4 mfma16(float4 a, float4 b, f32x4 c) {
  return __builtin_amdgcn_mfma_f32_16x16x32_f16(
      __builtin_bit_cast(h8, a), __builtin_bit_cast(h8, b), c, 0, 0, 0);
}

__device__ __forceinline__ float4 pack8(const float* p) {
  h1 v[8];
  #pragma unroll
  for (int j = 0; j < 8; ++j) v[j] = (h1)p[j];
  return *reinterpret_cast<float4*>(v);
}

// packed row prow = unit*4 + gate  ->  original row = gate*128 + unit
__device__ __host__ __forceinline__ int origrow(int prow) { return (prow & 3) * 128 + (prow >> 2); }

// ---- pack kernel: fragment-ordered fp16 weights into d_ws ----
// frag 0..127:   Whh0  (g0 h0-part)   idx = nt*4+kt
// frag 128..255: Wih1  (g1 h0-part)
// frag 256..383: Whh1  (g1 h1-part)
// lane l of frag: W[origrow(nt*16 + (l&15))][kt*32 + (l>>4)*8 + j], j=0..7 (fp16, 16B)
__global__ __launch_bounds__(256) void dnc_packf_kernel(
    const float* __restrict__ Whh0, const float* __restrict__ Wih1,
    const float* __restrict__ Whh1, float4* __restrict__ ws)
{
  int i = blockIdx.x * 256 + threadIdx.x;
  if (i >= 384 * 64) return;
  int l = i & 63, frag = i >> 6;
  int m = frag >> 7, f = frag & 127;
  int nt = f >> 2, kt = f & 3;
  int r = origrow(nt * 16 + (l & 15));
  int k0 = kt * 32 + (l >> 4) * 8;
  const float* W = (m == 0) ? Whh0 : (m == 1) ? Wih1 : Whh1;
  ws[i] = pack8(W + (size_t)r * HID + k0);
}

__global__ __launch_bounds__(BLK)
void dnc_mfma_kernel(
    const float* __restrict__ x,
    const float* __restrict__ Wih0, const float* __restrict__ Whh0, const float* __restrict__ b0,
    const float* __restrict__ Wih1, const float* __restrict__ Whh1, const float* __restrict__ b1,
    const float* __restrict__ Wif,  const float* __restrict__ bif,
    const float* __restrict__ Wout, const float* __restrict__ bout,
    const float4* __restrict__ wsT,
    float* __restrict__ out)
{
  // ---- LDS (~128 KB; 32 blocks -> 1/CU, co-residency irrelevant) ----
  __shared__ __align__(16) float4 s_w0f[32*64];     // Wih0 frags (K=32 padded inp ktile)
  __shared__ __align__(16) float4 s_wiff[24*64];    // Wif frags (6 ntiles x 4 ktiles)
  __shared__ __align__(16) h1 s_h0f[16*16*8];       // h0 fragments [kg][b][8]
  __shared__ __align__(16) h1 s_h1f[16*16*8];
  __shared__ __align__(16) h1 s_ctf[16*16*8];       // clipped ctrl fragments
  __shared__ __align__(16) h1 s_inpf[4*16*8];       // inp fragments: x(0-9),pad,rv(12-31)
  __shared__ float s_c0[GB][HID], s_c1[GB][HID];    // LSTM cell states
  __shared__ float s_ctrl32[GB][HID];               // fp32 ctrl for epilogue
  __shared__ float s_mem[GB][NC][CW];
  __shared__ float s_link[GB][NC][NC];
  __shared__ float s_rk[GB][CW], s_wk[GB][CW], s_er[GB][CW], s_wv[GB][CW];
  __shared__ float s_sc[GB][8], s_mraw[GB][4];
  __shared__ float s_usage[GB][NC], s_u[GB][NC], s_prec[GB][NC], s_prec2[GB][NC];
  __shared__ float s_rw[GB][NC], s_ww[GB][NC], s_cw[GB][NC], s_cr[GB][NC];
  __shared__ float s_fwd[GB][NC], s_bwd[GB][NC];
  __shared__ float s_rv[GB][CW];

  const int tid = threadIdx.x;
  const int l = tid & 63, w = tid >> 6;
  const int col = l & 15, g4 = l >> 4, q4 = l & 3;
  const int bbase = blockIdx.x * GB;

  // ---- init: Wih0 fragments (K layout: k<10 -> x col k; 10,11 -> 0; >=12 -> col k-2) ----
  for (int idx = tid; idx < 32*64; idx += BLK) {
    int nt = idx >> 6, ll = idx & 63;
    int r = origrow(nt*16 + (ll & 15));
    int kg = ll >> 4;
    float tmp[8];
    #pragma unroll
    for (int j = 0; j < 8; ++j) {
      int k = kg*8 + j;
      int cc = (k < 10) ? k : ((k < 12) ? -1 : (k - 2));
      tmp[j] = (cc < 0) ? 0.f : Wih0[r*(NIN+CW) + cc];
    }
    s_w0f[idx] = pack8(tmp);
  }
  // Wif fragments (N padded 88->96)
  for (int idx = tid; idx < 24*64; idx += BLK) {
    int f = idx >> 6, ll = idx & 63;
    int nt = f >> 2, kt = f & 3;
    int q = nt*16 + (ll & 15);
    int k0 = kt*32 + (ll >> 4)*8;
    float tmp[8];
    #pragma unroll
    for (int j = 0; j < 8; ++j) tmp[j] = (q < NIF) ? Wif[q*HID + k0 + j] : 0.f;
    s_wiff[idx] = pack8(tmp);
  }
  // zero state
  for (int idx = tid; idx < 16*16*8; idx += BLK) {
    s_h0f[idx] = (h1)0.f; s_h1f[idx] = (h1)0.f; s_ctf[idx] = (h1)0.f;
  }
  if (tid < 4*16*8) s_inpf[tid] = (h1)0.f;
  for (int idx = tid; idx < GB*HID; idx += BLK) { int b = idx >> 7, u = idx & 127;
    s_c0[b][u] = 0.f; s_c1[b][u] = 0.f; s_ctrl32[b][u] = 0.f; }
  for (int idx = tid; idx < GB*NC*CW; idx += BLK) { int b = idx/(NC*CW), e = idx%(NC*CW);
    s_mem[b][e/CW][e%CW] = 0.f; }
  for (int idx = tid; idx < GB*NC*NC; idx += BLK) { int b = idx/(NC*NC), e = idx%(NC*NC);
    s_link[b][e/NC][e%NC] = 0.f; }
  if (tid < GB*NC) { int b = tid & 15, n = tid >> 4;
    s_usage[b][n] = 0.f; s_prec[b][n] = 0.f; s_rw[b][n] = 0.f; s_ww[b][n] = 0.f; }
  for (int idx = tid; idx < GB*CW; idx += BLK) { int b = idx/CW, c = idx%CW; s_rv[b][c] = 0.f; }
  if (tid < GB*NIN) { int b = tid/NIN, i = tid - b*NIN;
    float v = x[((size_t)(bbase+b)*NT + 0)*NIN + i];
    s_inpf[((i>>3)*16 + b)*8 + (i&7)] = (h1)v;
  }
  // biases (per lane col side)
  const float b0v0 = b0[origrow((w*4+0)*16+col)], b0v1 = b0[origrow((w*4+1)*16+col)];
  const float b0v2 = b0[origrow((w*4+2)*16+col)], b0v3 = b0[origrow((w*4+3)*16+col)];
  const float b1v0 = b1[origrow((w*4+0)*16+col)], b1v1 = b1[origrow((w*4+1)*16+col)];
  const float b1v2 = b1[origrow((w*4+2)*16+col)], b1v3 = b1[origrow((w*4+3)*16+col)];
  float bifv = 0.f;
  if (w < 6) { int q = w*16 + col; bifv = (q < NIF) ? bif[q] : 0.f; }
  __syncthreads();

  const float4* h0fp = (const float4*)s_h0f;
  const float4* h1fp = (const float4*)s_h1f;
  const float4* ctfp = (const float4*)s_ctf;
  const float4* inpfp = (const float4*)s_inpf;

  // ---- DNC tail: 6 barriered phases, parallel over batch x cell ----
  auto dnc_phases = [&](bool run) {
    // H: usage/psi + write-content sims + modes softmax
    if (run) {
      if (tid < GB*NC) {
        int b = tid & 15, n = tid >> 4;
        float fg = s_sc[b][2];
        float psi = 1.f - fg * s_rw[b][n];
        float u = s_usage[b][n], wq = s_ww[b][n];
        u = (u + wq - u*wq) * psi;
        s_usage[b][n] = u;
        s_u[b][n] = 1e-6f + (1.0f - 1e-6f) * u;
        float dot = 0.f, mn = 0.f, kn = 0.f;
        #pragma unroll
        for (int c = 0; c < CW; ++c) {
          float m = s_mem[b][n][c], k = s_wk[b][c];
          dot += k*m; mn += m*m; kn += k*k;
        }
        s_cw[b][n] = dot * rcpf(sqrtf(kn)*sqrtf(mn) + 1e-6f) * s_sc[b][1];
      } else if (tid < GB*NC + GB) {
        int b = tid - GB*NC;
        float m0 = s_mraw[b][0], m1 = s_mraw[b][1], m2 = s_mraw[b][2];
        float mm = fmaxf(m0, fmaxf(m1, m2));
        float e0 = __expf(m0-mm), e1 = __expf(m1-mm), e2 = __expf(m2-mm);
        float es = rcpf(e0+e1+e2);
        s_sc[b][5] = e0*es; s_sc[b][6] = e1*es; s_sc[b][7] = e2*es;
      }
    }
    __syncthreads();
    // I: cw softmax + rank-based allocation + new ww
    if (run && tid < GB*NC) {
      int b = tid & 15, n = tid >> 4;
      float mx = -1e30f;
      #pragma unroll
      for (int m = 0; m < NC; ++m) mx = fmaxf(mx, s_cw[b][m]);
      float sm = 0.f;
      #pragma unroll
      for (int m = 0; m < NC; ++m) sm += __expf(s_cw[b][m]-mx);
      float cwv = __expf(s_cw[b][n]-mx) * rcpf(sm);
      float un = s_u[b][n];
      float excl = 1.f;
      #pragma unroll
      for (int m = 0; m < NC; ++m) {
        float um = s_u[b][m];
        bool before = (um < un) || (um == un && m < n);
        excl *= before ? um : 1.f;
      }
      float alloc = (1.f - un) * excl;
      float ga = s_sc[b][3], gw = s_sc[b][4];
      s_ww[b][n] = gw * (ga*alloc + (1.f-ga)*cwv);
    }
    __syncthreads();
    // J: memory write + link update + prec2
    if (run) {
      for (int e = tid; e < GB*NC*CW; e += BLK) {
        int b = e/(NC*CW), rr = (e/CW) % NC, c = e % CW;
        float wq = s_ww[b][rr];
        s_mem[b][rr][c] = s_mem[b][rr][c]*(1.f - wq*s_er[b][c]) + wq*s_wv[b][c];
      }
      for (int e = tid; e < GB*NC*NC; e += BLK) {
        int b = e/(NC*NC), i2 = (e/NC) % NC, j2 = e % NC;
        float wi = s_ww[b][i2], wj = s_ww[b][j2];
        float ln = (1.f - wi - wj)*s_link[b][i2][j2] + wi*s_prec[b][j2];
        s_link[b][i2][j2] = (i2==j2) ? 0.f : ln;
      }
      if (tid < GB*NC) {
        int b = tid & 15, n = tid >> 4;
        float sw2 = 0.f;
        #pragma unroll
        for (int m = 0; m < NC; ++m) sw2 += s_ww[b][m];
        s_prec2[b][n] = (1.f - sw2)*s_prec[b][n] + s_ww[b][n];
      }
    }
    __syncthreads();
    // K: commit prec, fwd/bwd (new link, old rw), read-content sims (new mem)
    if (run) {
      if (tid < GB*NC) {
        int b = tid & 15, m = tid >> 4;
        s_prec[b][m] = s_prec2[b][m];
        float a = 0.f;
        #pragma unroll
        for (int n = 0; n < NC; ++n) a += s_rw[b][n]*s_link[b][m][n];
        s_fwd[b][m] = a;
      } else if (tid < 2*GB*NC) {
        int tt = tid - GB*NC, b = tt & 15, m = tt >> 4;
        float a = 0.f;
        #pragma unroll
        for (int n = 0; n < NC; ++n) a += s_rw[b][n]*s_link[b][n][m];
        s_bwd[b][m] = a;
      } else if (tid < 3*GB*NC) {
        int tt = tid - 2*GB*NC, b = tt & 15, n = tt >> 4;
        float dot = 0.f, mn = 0.f, kn = 0.f;
        #pragma unroll
        for (int c = 0; c < CW; ++c) {
          float m = s_mem[b][n][c], k = s_rk[b][c];
          dot += k*m; mn += m*m; kn += k*k;
        }
        s_cr[b][n] = dot * rcpf(sqrtf(kn)*sqrtf(mn) + 1e-6f) * s_sc[b][0];
      }
    }
    __syncthreads();
    // L: cr softmax + new read weights
    if (run && tid < GB*NC) {
      int b = tid & 15, n = tid >> 4;
      float mx = -1e30f;
      #pragma unroll
      for (int m = 0; m < NC; ++m) mx = fmaxf(mx, s_cr[b][m]);
      float sm = 0.f;
      #pragma unroll
      for (int m = 0; m < NC; ++m) sm += __expf(s_cr[b][m]-mx);
      float cr = __expf(s_cr[b][n]-mx)*rcpf(sm);
      s_rw[b][n] = s_sc[b][5]*s_bwd[b][n] + s_sc[b][6]*cr + s_sc[b][7]*s_fwd[b][n];
    }
    __syncthreads();
    // M: rv + write rv into inp fragments (k = 12+c)
    if (run && tid < GB*CW) {
      int b = tid & 15, c = tid >> 4;
      float a = 0.f;
      #pragma unroll
      for (int n = 0; n < NC; ++n) a += s_rw[b][n]*s_mem[b][n][c];
      s_rv[b][c] = a;
      int k = 12 + c;
      s_inpf[((k>>3)*16 + b)*8 + (k&7)] = (h1)a;
    }
    __syncthreads();
  };

  // ---- LSTM layer: quad-broadcast gates, dedup ntile=q4, write fragments ----
  auto lstm_layer = [&](f32x4 ac0, f32x4 ac1, f32x4 ac2, f32x4 ac3,
                        float (*cst)[HID], h1* hf, bool isL1) {
    float GI[4] = {0,0,0,0}, GF[4] = {0,0,0,0}, GG[4] = {0,0,0,0}, GO[4] = {0,0,0,0};
    #pragma unroll
    for (int r = 0; r < 4; ++r) {
      f32x4 A = (r==0) ? ac0 : (r==1) ? ac1 : (r==2) ? ac2 : ac3;
      #pragma unroll
      for (int i = 0; i < 4; ++i) {
        float t0 = bq0(A[i]), t1 = bq1(A[i]), t2 = bq2(A[i]), t3 = bq3(A[i]);
        GI[i] = (q4 == r) ? t0 : GI[i];
        GF[i] = (q4 == r) ? t1 : GF[i];
        GG[i] = (q4 == r) ? t2 : GG[i];
        GO[i] = (q4 == r) ? t3 : GO[i];
      }
    }
    const int u = (w*4 + q4)*4 + (col >> 2);
    #pragma unroll
    for (int i = 0; i < 4; ++i) {
      int b = g4*4 + i;
      float c = sigf(GF[i])*cst[b][u] + sigf(GI[i])*tanhf_(GG[i]);
      cst[b][u] = c;
      float h = sigf(GO[i])*tanhf_(c);
      hf[((u>>3)*16 + b)*8 + (u&7)] = (h1)h;
      if (isL1) {
        float cl = fminf(fmaxf(h, -20.f), 20.f);
        s_ctf[((u>>3)*16 + b)*8 + (u&7)] = (h1)cl;
        s_ctrl32[b][u] = cl;
      }
    }
  };

  for (int t = 0; t < NT; ++t) {
    // ===== S0: DNC tail for step t-1 (6 barriers) =====
    dnc_phases(t > 0);

    // ===== S1a: g0 (inp ktile + 4 Whh0 ktiles) and g1 h1-part (4 Whh1 ktiles) =====
    unsigned lnd = 0;
    asm volatile("" : "+v"(lnd));   // defeat LICM hoisting of loop-invariant WS loads
    const float4* WS = (const float4*)((const char*)wsT + lnd);

    float4 ai  = inpfp[g4*16 + col];
    float4 a00 = h0fp[(0*4+g4)*16 + col], a01 = h0fp[(1*4+g4)*16 + col];
    float4 a02 = h0fp[(2*4+g4)*16 + col], a03 = h0fp[(3*4+g4)*16 + col];
    float4 a10 = h1fp[(0*4+g4)*16 + col], a11 = h1fp[(1*4+g4)*16 + col];
    float4 a12 = h1fp[(2*4+g4)*16 + col], a13 = h1fp[(3*4+g4)*16 + col];

    f32x4 acc0 = {b0v0,b0v0,b0v0,b0v0}, acc1 = {b0v1,b0v1,b0v1,b0v1};
    f32x4 acc2 = {b0v2,b0v2,b0v2,b0v2}, acc3 = {b0v3,b0v3,b0v3,b0v3};
    f32x4 gcc0 = {b1v0,b1v0,b1v0,b1v0}, gcc1 = {b1v1,b1v1,b1v1,b1v1};
    f32x4 gcc2 = {b1v2,b1v2,b1v2,b1v2}, gcc3 = {b1v3,b1v3,b1v3,b1v3};

#define G0IT(ACC, IT)                                                   \
    ACC = mfma16(ai,  s_w0f[(w*4+IT)*64 + l], ACC);                     \
    ACC = mfma16(a00, WS[((w*4+IT)*4+0)*64 + l], ACC);                  \
    ACC = mfma16(a01, WS[((w*4+IT)*4+1)*64 + l], ACC);                  \
    ACC = mfma16(a02, WS[((w*4+IT)*4+2)*64 + l], ACC);                  \
    ACC = mfma16(a03, WS[((w*4+IT)*4+3)*64 + l], ACC);
    G0IT(acc0, 0) G0IT(acc1, 1) G0IT(acc2, 2) G0IT(acc3, 3)
#undef G0IT
#define G1H1(ACC, IT)                                                   \
    ACC = mfma16(a10, WS[(256+(w*4+IT)*4+0)*64 + l], ACC);              \
    ACC = mfma16(a11, WS[(256+(w*4+IT)*4+1)*64 + l], ACC);              \
    ACC = mfma16(a12, WS[(256+(w*4+IT)*4+2)*64 + l], ACC);              \
    ACC = mfma16(a13, WS[(256+(w*4+IT)*4+3)*64 + l], ACC);
    G1H1(gcc0, 0) G1H1(gcc1, 1) G1H1(gcc2, 2) G1H1(gcc3, 3)
#undef G1H1
    __syncthreads();   // b7: all h0f/h1f/inpf reads done

    // ===== S1b: LSTM0 -> h0f =====
    lstm_layer(acc0, acc1, acc2, acc3, s_c0, s_h0f, false);
    __syncthreads();   // b8: h0f(t) visible

    // ===== S2: g1 += Wih1*h0(t), LSTM1 -> h1f/ctf =====
    {
      float4 ah0 = h0fp[(0*4+g4)*16 + col], ah1 = h0fp[(1*4+g4)*16 + col];
      float4 ah2 = h0fp[(2*4+g4)*16 + col], ah3 = h0fp[(3*4+g4)*16 + col];
#define G1H0(ACC, IT)                                                   \
      ACC = mfma16(ah0, WS[(128+(w*4+IT)*4+0)*64 + l], ACC);            \
      ACC = mfma16(ah1, WS[(128+(w*4+IT)*4+1)*64 + l], ACC);            \
      ACC = mfma16(ah2, WS[(128+(w*4+IT)*4+2)*64 + l], ACC);            \
      ACC = mfma16(ah3, WS[(128+(w*4+IT)*4+3)*64 + l], ACC);
      G1H0(gcc0, 0) G1H0(gcc1, 1) G1H0(gcc2, 2) G1H0(gcc3, 3)
#undef G1H0
      lstm_layer(gcc0, gcc1, gcc2, gcc3, s_c1, s_h1f, true);
    }
    __syncthreads();   // b9: h1f/ctf/ctrl32 visible

    // ===== S3: xi GEMM + fused transforms (waves 0-5) | x(t+1) prefetch (waves 6-7) =====
    if (w < 6) {
      float4 ac0 = ctfp[(0*4+g4)*16 + col], ac1 = ctfp[(1*4+g4)*16 + col];
      float4 ac2 = ctfp[(2*4+g4)*16 + col], ac3 = ctfp[(3*4+g4)*16 + col];
      f32x4 acc = {bifv, bifv, bifv, bifv};
      acc = mfma16(ac0, s_wiff[(w*4+0)*64 + l], acc);
      acc = mfma16(ac1, s_wiff[(w*4+1)*64 + l], acc);
      acc = mfma16(ac2, s_wiff[(w*4+2)*64 + l], acc);
      acc = mfma16(ac3, s_wiff[(w*4+3)*64 + l], acc);
      int q = w*16 + col;
      if (q < NIF) {
        #pragma unroll
        for (int i = 0; i < 4; ++i) {
          float a = acc[i];
          int b = g4*4 + i;
          if      (q < 20)  s_rk[b][q]    = tanhf_(a);
          else if (q == 20) s_sc[b][0]    = splus(a);
          else if (q < 41)  s_wk[b][q-21] = tanhf_(a);
          else if (q == 41) s_sc[b][1]    = splus(a);
          else if (q < 62)  s_er[b][q-42] = sigf(a);
          else if (q < 82)  s_wv[b][q-62] = tanhf_(a);
          else if (q == 82) s_sc[b][2]    = sigf(a);
          else if (q == 83) s_sc[b][3]    = sigf(a);
          else if (q == 84) s_sc[b][4]    = sigf(a);
          else              s_mraw[b][q-85] = a;
        }
      }
    } else {
      for (int e = (w-6)*64 + l; e < GB*NIN; e += 128) {
        int b = e/NIN, i = e - b*NIN;
        if (t+1 < NT) {
          float v = x[((size_t)(bbase+b)*NT + (t+1))*NIN + i];
          s_inpf[((i>>3)*16 + b)*8 + (i&7)] = (h1)v;
        }
      }
    }
    __syncthreads();   // b10
  }

  // ---- final DNC tail for t = NT-1 ----
  dnc_phases(true);

  // ---- epilogue: y = [ctrl, rv] @ Wout^T + bout ----
  if (tid < GB*NOUT) {
    int b = tid & 15, o = tid >> 4;
    float a = bout[o];
    const float* Wr = Wout + o*(HID+CW);
    #pragma unroll 4
    for (int k = 0; k < HID; ++k) a += Wr[k]*s_ctrl32[b][k];
    #pragma unroll
    for (int c = 0; c < CW; ++c) a += Wr[HID+c]*s_rv[b][c];
    out[(size_t)(bbase+b)*NOUT + o] = a;
  }
}

extern "C" void kernel_launch(void* const* d_in, const int* in_sizes, int n_in,
                              void* d_out, int out_size, void* d_ws, size_t ws_size,
                              hipStream_t stream) {
  (void)in_sizes; (void)n_in; (void)out_size; (void)ws_size;
  const float* x    = (const float*)d_in[0];
  const float* Wih0 = (const float*)d_in[1];
  const float* Whh0 = (const float*)d_in[2];
  const float* b0   = (const float*)d_in[3];
  const float* Wih1 = (const float*)d_in[4];
  const float* Whh1 = (const float*)d_in[5];
  const float* b1   = (const float*)d_in[6];
  const float* Wif  = (const float*)d_in[7];
  const float* bif  = (const float*)d_in[8];
  const float* Wout = (const float*)d_in[9];
  const float* bout = (const float*)d_in[10];
  float* out = (float*)d_out;
  float4* ws = (float4*)d_ws;

  dnc_packf_kernel<<<dim3(96), dim3(256), 0, stream>>>(Whh0, Wih1, Whh1, ws);
  dnc_mfma_kernel<<<dim3(NWG), dim3(BLK), 0, stream>>>(
      x, Wih0, Whh0, b0, Wih1, Whh1, b1, Wif, bif, Wout, bout, ws, out);
}